// Round 9
// baseline (139.064 us; speedup 1.0000x reference)
//
#include <hip/hip_runtime.h>

constexpr int Bn = 16;
constexpr int Tn = 512;
constexpr int Dn = 256;
constexpr int Vn = 4233;
constexpr int Vp = 4352;   // V padded to 34*128 (rows 4233.. are zeros)
constexpr int Ln = 64;     // LMAX
constexpr int Un = 80;     // glg2/pmat row stride (65 used)
constexpr int CS = 68;     // ctc LDS row stride in floats
constexpr int NCB = 34;    // number of 128-wide vocab column blocks
constexpr int Mtot = Bn * Tn;  // 8192

#define LN2     0.6931471805599453f
#define INV_LN2 1.4426950408889634f

typedef __attribute__((ext_vector_type(8))) short short8;
typedef __attribute__((ext_vector_type(4))) float f32x4;

__device__ __forceinline__ float lg2(float x) { return __builtin_amdgcn_logf(x); }
__device__ __forceinline__ float ex2(float x) { return __builtin_amdgcn_exp2f(x); }

__device__ __forceinline__ unsigned short cvt_bf16(float f) {
    unsigned int u = __float_as_uint(f);
    u = (u + 0x7fffu + ((u >> 16) & 1u)) >> 16;
    return (unsigned short)u;
}

// async global->LDS, 16B per lane
__device__ __forceinline__ void gl_lds16(const void* g, void* l) {
    __builtin_amdgcn_global_load_lds(
        (const __attribute__((address_space(1))) void*)g,
        (__attribute__((address_space(3))) void*)l,
        16, 0, 0);
}

// f32 value from lane-1 (wave_shr:1); lane 0 takes `edge`
__device__ __forceinline__ float dpp_shr1_f(float v, float edge) {
    return __int_as_float(__builtin_amdgcn_update_dpp(
        __float_as_int(edge), __float_as_int(v), 0x138, 0xF, 0xF, false));
}

// f64 value from lane-1 (wave_shr:1); lane 0 takes 0.0
__device__ __forceinline__ double dpp_shr1_d(double v) {
    union { double d; int i[2]; } u, r;
    u.d = v;
    r.i[0] = __builtin_amdgcn_update_dpp(0, u.i[0], 0x138, 0xF, 0xF, false);
    r.i[1] = __builtin_amdgcn_update_dpp(0, u.i[1], 0x138, 0xF, 0xF, false);
    return r.d;
}

// wave-wide int max -> uniform value in all lanes (4 DPP stages + 4 readlanes)
__device__ __forceinline__ int wave_imax(int v) {
    int t;
    t = __builtin_amdgcn_update_dpp(v, v, 0xB1,  0xF, 0xF, false); v = (t > v) ? t : v; // xor1
    t = __builtin_amdgcn_update_dpp(v, v, 0x4E,  0xF, 0xF, false); v = (t > v) ? t : v; // xor2
    t = __builtin_amdgcn_update_dpp(v, v, 0x141, 0xF, 0xF, false); v = (t > v) ? t : v; // xor4
    t = __builtin_amdgcn_update_dpp(v, v, 0x140, 0xF, 0xF, false); v = (t > v) ? t : v; // xor8
    int a = __builtin_amdgcn_readlane(v, 0);
    int b = __builtin_amdgcn_readlane(v, 16);
    int c = __builtin_amdgcn_readlane(v, 32);
    int d = __builtin_amdgcn_readlane(v, 48);
    int ab = (a > b) ? a : b;
    int cd = (c > d) ? c : d;
    return (ab > cd) ? ab : cd;
}

// ---------------- conversion prep (zeroes d_out) ----------------
__global__ __launch_bounds__(256) void conv(
    const float* __restrict__ hs, const float* __restrict__ W,
    const float* __restrict__ bias, const int* __restrict__ ys,
    unsigned short* __restrict__ hs_b, unsigned short* __restrict__ w_b,
    float* __restrict__ gbias, float* __restrict__ out)
{
    const int gid = blockIdx.x * 256 + threadIdx.x;
    const int stride = gridDim.x * 256;
    const float4* hs4 = (const float4*)hs;
    const float4* W4  = (const float4*)W;

    if (gid == 0) out[0] = 0.0f;   // atomic target for ctc_fwd

    for (int i = gid; i < (Bn * Tn * Dn) / 4; i += stride) {
        float4 v = hs4[i];
        ushort4 o = make_ushort4(cvt_bf16(v.x), cvt_bf16(v.y), cvt_bf16(v.z), cvt_bf16(v.w));
        *(ushort4*)(&hs_b[i * 4]) = o;
    }
    for (int i = gid; i < Vp * (Dn / 4); i += stride) {
        int row = i >> 6;
        float4 v = make_float4(0.f, 0.f, 0.f, 0.f);
        if (row < Vn) v = W4[i];
        ushort4 o = make_ushort4(cvt_bf16(v.x), cvt_bf16(v.y), cvt_bf16(v.z), cvt_bf16(v.w));
        *(ushort4*)(&w_b[i * 4]) = o;
    }
    for (int i = gid; i < Bn * 128; i += stride) {
        int b = i >> 7;
        int u = i & 127;
        int v = (u == 0) ? 0 : ((u <= Ln) ? ys[b * Ln + u - 1] : -1);
        gbias[i] = (v >= 0) ? bias[v] : 0.0f;
    }
}

// ---------------- unified GEMM (r5 exact: 32KB LDS, 3 blocks/CU) ----------------
__global__ __launch_bounds__(256) void gemm_se(
    const unsigned short* __restrict__ hs_b, const unsigned short* __restrict__ w_b,
    const int* __restrict__ ys, const float* __restrict__ bias,
    const float* __restrict__ gbias, float* __restrict__ sep,
    float* __restrict__ glg2)
{
    __shared__ __align__(16) short lsA[128 * 64];
    __shared__ __align__(16) short lsB[128 * 64];

    const int tid = threadIdx.x;
    const int lane = tid & 63;
    const int w = tid >> 6;
    const int lr = lane & 15;
    const int kq = lane >> 4;
    const int m0 = blockIdx.x * 128;
    const int mw = w * 32;
    const bool gather = (blockIdx.y == NCB);
    const int b = blockIdx.x >> 2;

    const int srow = lane >> 3;
    const int scg  = (lane & 7) ^ (srow & 7);
    const int scol = scg * 8;

    const unsigned short* bptr[4];
    #pragma unroll
    for (int j = 0; j < 4; ++j) {
        int c = w * 4 + j;
        int row = c * 8 + srow;
        int v;
        if (gather) {
            if (row == 0) v = 0;
            else if (row <= Ln) v = ys[b * Ln + row - 1];
            else v = Vn + 32;                 // zero pad row of w_b
        } else {
            v = blockIdx.y * 128 + row;
        }
        bptr[j] = w_b + (size_t)v * Dn + scol;
    }

    f32x4 acc[2][8];
    #pragma unroll
    for (int mf = 0; mf < 2; ++mf)
        #pragma unroll
        for (int nf = 0; nf < 8; ++nf)
            acc[mf][nf] = (f32x4){0.f, 0.f, 0.f, 0.f};

    for (int ks = 0; ks < 4; ++ks) {
        const int k0 = ks * 64;
        __syncthreads();
        #pragma unroll
        for (int j = 0; j < 4; ++j) {
            int c = w * 4 + j;
            int row = c * 8 + srow;
            gl_lds16(hs_b + (size_t)(m0 + row) * Dn + k0 + scol, (char*)lsA + c * 1024);
            gl_lds16(bptr[j] + k0,                               (char*)lsB + c * 1024);
        }
        __syncthreads();

        #pragma unroll
        for (int sub = 0; sub < 2; ++sub) {
            short8 af[2], bf[8];
            #pragma unroll
            for (int mf = 0; mf < 2; ++mf) {
                int row = mw + mf * 16 + lr;
                int cg = (sub * 4 + kq) ^ (row & 7);
                af[mf] = *(const short8*)(&lsA[row * 64 + cg * 8]);
            }
            #pragma unroll
            for (int nf = 0; nf < 8; ++nf) {
                int row = nf * 16 + lr;
                int cg = (sub * 4 + kq) ^ (row & 7);
                bf[nf] = *(const short8*)(&lsB[row * 64 + cg * 8]);
            }
            #pragma unroll
            for (int mf = 0; mf < 2; ++mf)
                #pragma unroll
                for (int nf = 0; nf < 8; ++nf)
                    acc[mf][nf] = __builtin_amdgcn_mfma_f32_16x16x32_bf16(
                        af[mf], bf[nf], acc[mf][nf], 0, 0, 0);
        }
    }

    if (!gather) {
        const int n0 = blockIdx.y * 128;
        float bcol[8]; bool valid[8];
        #pragma unroll
        for (int nf = 0; nf < 8; ++nf) {
            int col = n0 + nf * 16 + lr;
            valid[nf] = (col < Vn);
            bcol[nf] = valid[nf] ? bias[col] : 0.0f;
        }
        #pragma unroll
        for (int mf = 0; mf < 2; ++mf) {
            #pragma unroll
            for (int r = 0; r < 4; ++r) {
                float s = 0.0f;
                #pragma unroll
                for (int nf = 0; nf < 8; ++nf)
                    if (valid[nf]) s += __expf(acc[mf][nf][r] + bcol[nf]);
                #pragma unroll
                for (int off = 1; off < 16; off <<= 1) s += __shfl_xor(s, off, 64);
                if (lr == 0)
                    sep[(size_t)blockIdx.y * Mtot + m0 + mw + mf * 16 + kq * 4 + r] = s;
            }
        }
    } else {
        #pragma unroll
        for (int mf = 0; mf < 2; ++mf) {
            #pragma unroll
            for (int nf = 0; nf < 5; ++nf) {
                int u = nf * 16 + lr;
                float gv = gbias[b * 128 + u];
                #pragma unroll
                for (int r = 0; r < 4; ++r) {
                    int g = m0 + mw + mf * 16 + kq * 4 + r;
                    glg2[(size_t)g * Un + u] = (acc[mf][nf][r] + gv) * INV_LN2;
                }
            }
        }
    }
}

// ---------------- CTC forward (f64 chain, unnormalized) + normalizer ----------------
// (r5 exact — passed twice)
__global__ __launch_bounds__(256) void ctc_fwd(
    const float* __restrict__ pmat, const float* __restrict__ sep,
    const int* __restrict__ ys, const int* __restrict__ hlens,
    const int* __restrict__ ylens, float* __restrict__ out)
{
    __shared__ __align__(16) union SMem {
        struct {
            float ls[2][64 * CS + 4];
            double shO[64], shE[64], shZ[64];
            int   shX[64];
        } c;
        struct { float wsum[4]; } r;
    } sm;

    const int tid = threadIdx.x;
    const int l = tid & 63;
    const int w = tid >> 6;

    if (blockIdx.x >= 16) {
        const int b = blockIdx.x - 16;
        const int hl = hlens[b];
        float corrAcc = 0.0f;
        #pragma unroll
        for (int j = 0; j < 2; ++j) {
            int t = tid + j * 256;
            float s = 0.0f;
            #pragma unroll
            for (int c = 0; c < NCB; ++c)
                s += sep[(size_t)c * Mtot + b * Tn + t];
            if (t < hl) corrAcc += lg2(s);
        }
        #pragma unroll
        for (int off = 1; off < 64; off <<= 1) corrAcc += __shfl_xor(corrAcc, off, 64);
        if (l == 0) sm.r.wsum[w] = corrAcc;
        __syncthreads();
        if (tid == 0)
            atomicAdd(out, (sm.r.wsum[0] + sm.r.wsum[1] + sm.r.wsum[2] + sm.r.wsum[3])
                           * (LN2 / (float)Bn));
        return;
    }

    const int b = blockIdx.x;
    const int hl = hlens[b];
    int yl  = ys[b * Ln + l];
    int ylm = (l >= 1) ? ys[b * Ln + l - 1] : -1;
    const double aF = ((l >= 1) && (yl != ylm)) ? 1.0 : 0.0;

    const float* pm = pmat + (size_t)b * Tn * Un;

    #pragma unroll
    for (int j = 0; j < 4; ++j) {
        int i = tid + j * 256;
        int tt = i >> 4, u4 = (i & 15) * 4;
        float4 v = *(const float4*)(pm + (size_t)(1 + tt) * Un + u4);
        v.x = ex2(v.x); v.y = ex2(v.y); v.z = ex2(v.z); v.w = ex2(v.w);
        *(float4*)(&sm.c.ls[0][tt * CS + u4]) = v;
    }
    if (tid < 64) sm.c.ls[0][tid * CS + 64] = ex2(pm[(size_t)(1 + tid) * Un + 64]);
    __syncthreads();

    double o = (l == 0) ? (double)ex2(pm[1]) : 0.0;
    double e = (l == 0) ? (double)ex2(pm[0]) : 0.0;
    double z = 0.0;
    int ex = 0;

    float4 r4a = make_float4(0.f,0.f,0.f,0.f), r4b = r4a, r4c = r4a, r4d = r4a;
    float r1 = 0.0f;

    double qa0, qa1, qa2, qa3, ra0, ra1, ra2, ra3;
    double qb0, qb1, qb2, qb3, rb0, rb1, rb2, rb3;
    double qc0, qc1, qc2, qc3, rc0, rc1, rc2, rc3;

#define RENORM32 do { \
        double mm = fmax(fmax(o, e), z); \
        union { double d; unsigned int ui[2]; } um; um.d = mm; \
        int kk = (int)((um.ui[1] >> 20) & 2047u) - 1023; \
        int km = wave_imax(kk); \
        o = ldexp(o, -km); e = ldexp(e, -km); z = ldexp(z, -km); \
        ex += km; \
    } while (0)

#define STEPR(qv, rv) do { \
        double an = dpp_shr1_d(o); \
        double nO = fma(aF, an, o + e) * (rv); \
        double nE = (e + an) * (qv); \
        double nZ = (z + o) * (qv); \
        o = nO; e = nE; z = nZ; \
    } while (0)

#define LDA(base) do { \
        qa0 = (double)buf[(base) * CS];       ra0 = (double)buf[(base) * CS + 1 + l]; \
        qa1 = (double)buf[((base)+1) * CS];   ra1 = (double)buf[((base)+1) * CS + 1 + l]; \
        qa2 = (double)buf[((base)+2) * CS];   ra2 = (double)buf[((base)+2) * CS + 1 + l]; \
        qa3 = (double)buf[((base)+3) * CS];   ra3 = (double)buf[((base)+3) * CS + 1 + l]; \
    } while (0)
#define LDB(base) do { \
        qb0 = (double)buf[(base) * CS];       rb0 = (double)buf[(base) * CS + 1 + l]; \
        qb1 = (double)buf[((base)+1) * CS];   rb1 = (double)buf[((base)+1) * CS + 1 + l]; \
        qb2 = (double)buf[((base)+2) * CS];   rb2 = (double)buf[((base)+2) * CS + 1 + l]; \
        qb3 = (double)buf[((base)+3) * CS];   rb3 = (double)buf[((base)+3) * CS + 1 + l]; \
    } while (0)
#define LDC(base) do { \
        qc0 = (double)buf[(base) * CS];       rc0 = (double)buf[(base) * CS + 1 + l]; \
        qc1 = (double)buf[((base)+1) * CS];   rc1 = (double)buf[((base)+1) * CS + 1 + l]; \
        qc2 = (double)buf[((base)+2) * CS];   rc2 = (double)buf[((base)+2) * CS + 1 + l]; \
        qc3 = (double)buf[((base)+3) * CS];   rc3 = (double)buf[((base)+3) * CS + 1 + l]; \
    } while (0)

#define W4A do { STEPR(qa0,ra0); STEPR(qa1,ra1); STEPR(qa2,ra2); STEPR(qa3,ra3); } while (0)
#define W4B do { STEPR(qb0,rb0); STEPR(qb1,rb1); STEPR(qb2,rb2); STEPR(qb3,rb3); } while (0)
#define W4C do { STEPR(qc0,rc0); STEPR(qc1,rc1); STEPR(qc2,rc2); STEPR(qc3,rc3); } while (0)

#define STEPS(Joff, ACT) do { \
        RENORM32; \
        double q = (double)buf[(Joff) * CS]; \
        double r = (double)buf[(Joff) * CS + 1 + l]; \
        double an = dpp_shr1_d(o); \
        double nO = fma(aF, an, o + e) * r; \
        double nE = (e + an) * q; \
        double nZ = (z + o) * q; \
        bool act = (ACT); \
        o = act ? nO : o; e = act ? nE : e; z = act ? nZ : z; \
    } while (0)

    for (int c = 0; c < 8; ++c) {
        if (c < 7) {
            const int tb = 1 + (c + 1) * 64;
            { int i = tid;       int tt = i >> 4, u4 = (i & 15) * 4;
              r4a = (tb + tt < Tn) ? *(const float4*)(pm + (size_t)(tb + tt) * Un + u4) : make_float4(0.f,0.f,0.f,0.f); }
            { int i = tid + 256; int tt = i >> 4, u4 = (i & 15) * 4;
              r4b = (tb + tt < Tn) ? *(const float4*)(pm + (size_t)(tb + tt) * Un + u4) : make_float4(0.f,0.f,0.f,0.f); }
            { int i = tid + 512; int tt = i >> 4, u4 = (i & 15) * 4;
              r4c = (tb + tt < Tn) ? *(const float4*)(pm + (size_t)(tb + tt) * Un + u4) : make_float4(0.f,0.f,0.f,0.f); }
            { int i = tid + 768; int tt = i >> 4, u4 = (i & 15) * 4;
              r4d = (tb + tt < Tn) ? *(const float4*)(pm + (size_t)(tb + tt) * Un + u4) : make_float4(0.f,0.f,0.f,0.f); }
            if (tid < 64)
                r1 = (tb + tid < Tn) ? pm[(size_t)(tb + tid) * Un + 64] : 0.0f;
        }

        const float* buf = sm.c.ls[c & 1];

        if (c < 7) {
            if (hl >= (c + 1) * 64 + 1) {
                RENORM32;
                LDA(0); LDB(4);
                LDC(8);  W4A;
                LDA(12); W4B;
                LDB(16); W4C;
                LDC(20); W4A;
                LDA(24); W4B;
                LDB(28); W4C;
                LDC(32); W4A;
                LDA(36); W4B;
                RENORM32;
                LDB(40); W4C;
                LDC(44); W4A;
                LDA(48); W4B;
                LDB(52); W4C;
                LDC(56); W4A;
                LDA(60); W4B;
                W4C;
                W4A;
            } else {
                #pragma unroll 1
                for (int j = 0; j < 64; ++j)
                    STEPS(j, (c * 64 + 1 + j) < hl);
            }
        } else {
            if (hl >= Tn) {
                RENORM32;
                LDA(0); LDB(4);
                LDC(8);  W4A;
                LDA(12); W4B;
                LDB(16); W4C;
                LDC(20); W4A;
                LDA(24); W4B;
                LDB(28); W4C;
                LDC(32); W4A;
                LDA(36); W4B;
                RENORM32;
                LDB(40); W4C;
                LDC(44); W4A;
                LDA(48); W4B;
                LDB(52); W4C;
                LDC(56); W4A;
                LDA(60); W4B;
                W4C;
                STEPR(qa0, ra0); STEPR(qa1, ra1); STEPR(qa2, ra2);
            } else {
                #pragma unroll 1
                for (int j = 0; j < 63; ++j)
                    STEPS(j, (449 + j) < hl);
            }
        }

        if (c < 7) {
            const int tb = 1 + (c + 1) * 64;
            float* dst = sm.c.ls[(c + 1) & 1];
            { int i = tid;       int tt = i >> 4, u4 = (i & 15) * 4; float4 v = r4a;
              v.x = ex2(v.x); v.y = ex2(v.y); v.z = ex2(v.z); v.w = ex2(v.w);
              if (tb + tt >= Tn) v = make_float4(0.f,0.f,0.f,0.f);
              *(float4*)(&dst[tt * CS + u4]) = v; }
            { int i = tid + 256; int tt = i >> 4, u4 = (i & 15) * 4; float4 v = r4b;
              v.x = ex2(v.x); v.y = ex2(v.y); v.z = ex2(v.z); v.w = ex2(v.w);
              if (tb + tt >= Tn) v = make_float4(0.f,0.f,0.f,0.f);
              *(float4*)(&dst[tt * CS + u4]) = v; }
            { int i = tid + 512; int tt = i >> 4, u4 = (i & 15) * 4; float4 v = r4c;
              v.x = ex2(v.x); v.y = ex2(v.y); v.z = ex2(v.z); v.w = ex2(v.w);
              if (tb + tt >= Tn) v = make_float4(0.f,0.f,0.f,0.f);
              *(float4*)(&dst[tt * CS + u4]) = v; }
            { int i = tid + 768; int tt = i >> 4, u4 = (i & 15) * 4; float4 v = r4d;
              v.x = ex2(v.x); v.y = ex2(v.y); v.z = ex2(v.z); v.w = ex2(v.w);
              if (tb + tt >= Tn) v = make_float4(0.f,0.f,0.f,0.f);
              *(float4*)(&dst[tt * CS + u4]) = v; }
            if (tid < 64)
                dst[tid * CS + 64] = (tb + tid < Tn) ? ex2(r1) : 0.0f;
        }
        __syncthreads();
    }
#undef RENORM32
#undef STEPR
#undef LDA
#undef LDB
#undef LDC
#undef W4A
#undef W4B
#undef W4C
#undef STEPS

    if (tid < 64) { sm.c.shO[l] = o; sm.c.shE[l] = e; sm.c.shZ[l] = z; sm.c.shX[l] = ex; }
    __syncthreads();

    if (tid == 0) {
        int L = ylens[b];
        double vo = sm.c.shO[L - 1]; int xo = sm.c.shX[L - 1];
        double ve; int xe;
        if (L == 64) { ve = sm.c.shZ[63]; xe = sm.c.shX[63]; }
        else         { ve = sm.c.shE[L];  xe = sm.c.shX[L]; }
        int em = (xo > xe) ? xo : xe;
        double s = ldexp(vo, xo - em) + ldexp(ve, xe - em);
        union { double d; unsigned int ui[2]; } us; us.d = s;
        int ks = (int)((us.ui[1] >> 20) & 2047u) - 1023;
        double mant = ldexp(s, -ks);
        float ll = (lg2((float)mant) + (float)(ks + em)) * LN2;
        atomicAdd(out, -ll / (float)Bn);
    }
}

// ---------------- TIMING PROBE: f32 chain, renorm-8, scratch-only output ----------
// 16 blocks; identical chunk/staging structure to ctc_fwd's chain role but f32
// states (single-dpp shift, 2-cyc issue, no f64 cvt) and wave-uniform renorm
// every 8 steps. Runs the full 511 steps unconditionally (hl==Tn in this
// workload; control flow data-independent -> exact timing). Writes only pscr.
__global__ __launch_bounds__(256) void ctc_probe(
    const float* __restrict__ pmat, const int* __restrict__ ys,
    float* __restrict__ pscr)
{
    __shared__ __align__(16) float ls[2][64 * CS + 4];

    const int tid = threadIdx.x;
    const int l = tid & 63;

    const int b = blockIdx.x;
    int yl  = ys[b * Ln + l];
    int ylm = (l >= 1) ? ys[b * Ln + l - 1] : -1;
    const float aF = ((l >= 1) && (yl != ylm)) ? 1.0f : 0.0f;

    const float* pm = pmat + (size_t)b * Tn * Un;

    #pragma unroll
    for (int j = 0; j < 4; ++j) {
        int i = tid + j * 256;
        int tt = i >> 4, u4 = (i & 15) * 4;
        float4 v = *(const float4*)(pm + (size_t)(1 + tt) * Un + u4);
        v.x = ex2(v.x); v.y = ex2(v.y); v.z = ex2(v.z); v.w = ex2(v.w);
        *(float4*)(&ls[0][tt * CS + u4]) = v;
    }
    if (tid < 64) ls[0][tid * CS + 64] = ex2(pm[(size_t)(1 + tid) * Un + 64]);
    __syncthreads();

    float o = (l == 0) ? ex2(pm[1]) : 0.0f;
    float e = (l == 0) ? ex2(pm[0]) : 0.0f;
    float z = 0.0f;
    int ex = 0;

    float4 r4a = make_float4(0.f,0.f,0.f,0.f), r4b = r4a, r4c = r4a, r4d = r4a;
    float r1 = 0.0f;

    float qa0, qa1, qa2, qa3, ra0, ra1, ra2, ra3;
    float qb0, qb1, qb2, qb3, rb0, rb1, rb2, rb3;
    float qc0, qc1, qc2, qc3, rc0, rc1, rc2, rc3;

#define R8 do { \
        float mm = fmaxf(fmaxf(o, e), z); \
        bool nz = (mm > 0.0f); \
        int kk = nz ? ((int)((__float_as_uint(mm) >> 23) & 255u) - 127) : -100000; \
        int km = wave_imax(kk); \
        o = ldexpf(o, -km); e = ldexpf(e, -km); z = ldexpf(z, -km); \
        ex += km; \
    } while (0)

#define STEPF(qv, rv) do { \
        float an = dpp_shr1_f(o, 0.0f); \
        float nO = fmaf(aF, an, o + e) * (rv); \
        float nE = (e + an) * (qv); \
        float nZ = (z + o) * (qv); \
        o = nO; e = nE; z = nZ; \
    } while (0)

#define LFA(base) do { \
        qa0 = buf[(base) * CS];       ra0 = buf[(base) * CS + 1 + l]; \
        qa1 = buf[((base)+1) * CS];   ra1 = buf[((base)+1) * CS + 1 + l]; \
        qa2 = buf[((base)+2) * CS];   ra2 = buf[((base)+2) * CS + 1 + l]; \
        qa3 = buf[((base)+3) * CS];   ra3 = buf[((base)+3) * CS + 1 + l]; \
    } while (0)
#define LFB(base) do { \
        qb0 = buf[(base) * CS];       rb0 = buf[(base) * CS + 1 + l]; \
        qb1 = buf[((base)+1) * CS];   rb1 = buf[((base)+1) * CS + 1 + l]; \
        qb2 = buf[((base)+2) * CS];   rb2 = buf[((base)+2) * CS + 1 + l]; \
        qb3 = buf[((base)+3) * CS];   rb3 = buf[((base)+3) * CS + 1 + l]; \
    } while (0)
#define LFC(base) do { \
        qc0 = buf[(base) * CS];       rc0 = buf[(base) * CS + 1 + l]; \
        qc1 = buf[((base)+1) * CS];   rc1 = buf[((base)+1) * CS + 1 + l]; \
        qc2 = buf[((base)+2) * CS];   rc2 = buf[((base)+2) * CS + 1 + l]; \
        qc3 = buf[((base)+3) * CS];   rc3 = buf[((base)+3) * CS + 1 + l]; \
    } while (0)

#define WF4A do { STEPF(qa0,ra0); STEPF(qa1,ra1); STEPF(qa2,ra2); STEPF(qa3,ra3); } while (0)
#define WF4B do { STEPF(qb0,rb0); STEPF(qb1,rb1); STEPF(qb2,rb2); STEPF(qb3,rb3); } while (0)
#define WF4C do { STEPF(qc0,rc0); STEPF(qc1,rc1); STEPF(qc2,rc2); STEPF(qc3,rc3); } while (0)

    for (int c = 0; c < 8; ++c) {
        if (c < 7) {
            const int tb = 1 + (c + 1) * 64;
            { int i = tid;       int tt = i >> 4, u4 = (i & 15) * 4;
              r4a = (tb + tt < Tn) ? *(const float4*)(pm + (size_t)(tb + tt) * Un + u4) : make_float4(0.f,0.f,0.f,0.f); }
            { int i = tid + 256; int tt = i >> 4, u4 = (i & 15) * 4;
              r4b = (tb + tt < Tn) ? *(const float4*)(pm + (size_t)(tb + tt) * Un + u4) : make_float4(0.f,0.f,0.f,0.f); }
            { int i = tid + 512; int tt = i >> 4, u4 = (i & 15) * 4;
              r4c = (tb + tt < Tn) ? *(const float4*)(pm + (size_t)(tb + tt) * Un + u4) : make_float4(0.f,0.f,0.f,0.f); }
            { int i = tid + 768; int tt = i >> 4, u4 = (i & 15) * 4;
              r4d = (tb + tt < Tn) ? *(const float4*)(pm + (size_t)(tb + tt) * Un + u4) : make_float4(0.f,0.f,0.f,0.f); }
            if (tid < 64)
                r1 = (tb + tid < Tn) ? pm[(size_t)(tb + tid) * Un + 64] : 0.0f;
        }

        const float* buf = ls[c & 1];

        if (c < 7) {
            LFA(0); LFB(4);
            LFC(8);  R8; WF4A;   // w0
            LFA(12); WF4B;       // w1
            LFB(16); R8; WF4C;   // w2
            LFC(20); WF4A;       // w3
            LFA(24); R8; WF4B;   // w4
            LFB(28); WF4C;       // w5
            LFC(32); R8; WF4A;   // w6
            LFA(36); WF4B;       // w7
            LFB(40); R8; WF4C;   // w8
            LFC(44); WF4A;       // w9
            LFA(48); R8; WF4B;   // w10
            LFB(52); WF4C;       // w11
            LFC(56); R8; WF4A;   // w12
            LFA(60); WF4B;       // w13
            R8; WF4C;            // w14
            WF4A;                // w15
        } else {
            LFA(0); LFB(4);
            LFC(8);  R8; WF4A;
            LFA(12); WF4B;
            LFB(16); R8; WF4C;
            LFC(20); WF4A;
            LFA(24); R8; WF4B;
            LFB(28); WF4C;
            LFC(32); R8; WF4A;
            LFA(36); WF4B;
            LFB(40); R8; WF4C;
            LFC(44); WF4A;
            LFA(48); R8; WF4B;
            LFB(52); WF4C;
            LFC(56); R8; WF4A;
            LFA(60); WF4B;
            R8; WF4C;                                     // w14
            STEPF(qa0, ra0); STEPF(qa1, ra1); STEPF(qa2, ra2);  // tail 60-62
        }

        if (c < 7) {
            const int tb = 1 + (c + 1) * 64;
            float* dst = ls[(c + 1) & 1];
            { int i = tid;       int tt = i >> 4, u4 = (i & 15) * 4; float4 v = r4a;
              v.x = ex2(v.x); v.y = ex2(v.y); v.z = ex2(v.z); v.w = ex2(v.w);
              if (tb + tt >= Tn) v = make_float4(0.f,0.f,0.f,0.f);
              *(float4*)(&dst[tt * CS + u4]) = v; }
            { int i = tid + 256; int tt = i >> 4, u4 = (i & 15) * 4; float4 v = r4b;
              v.x = ex2(v.x); v.y = ex2(v.y); v.z = ex2(v.z); v.w = ex2(v.w);
              if (tb + tt >= Tn) v = make_float4(0.f,0.f,0.f,0.f);
              *(float4*)(&dst[tt * CS + u4]) = v; }
            { int i = tid + 512; int tt = i >> 4, u4 = (i & 15) * 4; float4 v = r4c;
              v.x = ex2(v.x); v.y = ex2(v.y); v.z = ex2(v.z); v.w = ex2(v.w);
              if (tb + tt >= Tn) v = make_float4(0.f,0.f,0.f,0.f);
              *(float4*)(&dst[tt * CS + u4]) = v; }
            { int i = tid + 768; int tt = i >> 4, u4 = (i & 15) * 4; float4 v = r4d;
              v.x = ex2(v.x); v.y = ex2(v.y); v.z = ex2(v.z); v.w = ex2(v.w);
              if (tb + tt >= Tn) v = make_float4(0.f,0.f,0.f,0.f);
              *(float4*)(&dst[tt * CS + u4]) = v; }
            if (tid < 64)
                dst[tid * CS + 64] = (tb + tid < Tn) ? ex2(r1) : 0.0f;
        }
        __syncthreads();
    }
#undef R8
#undef STEPF
#undef LFA
#undef LFB
#undef LFC
#undef WF4A
#undef WF4B
#undef WF4C

    // keep every chain value live (no DCE); scratch-only write
    pscr[b * 256 + tid] = (o + e + z) + (float)ex;
}

extern "C" void kernel_launch(void* const* d_in, const int* in_sizes, int n_in,
                              void* d_out, int out_size, void* d_ws, size_t ws_size,
                              hipStream_t stream) {
    const float* hs    = (const float*)d_in[0];
    const int*   hlens = (const int*)d_in[1];
    const int*   ys    = (const int*)d_in[2];
    const int*   ylens = (const int*)d_in[3];
    const float* W     = (const float*)d_in[4];
    const float* bias  = (const float*)d_in[5];
    float* out = (float*)d_out;

    char* ws = (char*)d_ws;
    unsigned short* hs_b = (unsigned short*)(ws);                       // 4,194,304 B
    unsigned short* w_b  = (unsigned short*)(ws + 4194304);             // 2,228,224 B
    float* glg2  = (float*)(ws + 6422528);                              // 2,621,440 B
    float* sep   = (float*)(ws + 9043968);                              // 1,114,112 B
    float* gbias = (float*)(ws + 10158080);                             //     8,192 B
    float* pscr  = (float*)(ws + 12582912);                             // probe scratch

    conv<<<1024, 256, 0, stream>>>(hs, W, bias, ys, hs_b, w_b, gbias, out);
    gemm_se<<<dim3(64, NCB + 1), 256, 0, stream>>>(hs_b, w_b, ys, bias, gbias, sep, glg2);
    ctc_fwd<<<32, 256, 0, stream>>>(glg2, sep, ys, hlens, ylens, out);
    ctc_probe<<<16, 256, 0, stream>>>(glg2, ys, pscr);   // timing probe, scratch-only
}

// Round 11
// 113.791 us; speedup vs baseline: 1.2221x; 1.2221x over previous
//
#include <hip/hip_runtime.h>

constexpr int Bn = 16;
constexpr int Tn = 512;
constexpr int Dn = 256;
constexpr int Vn = 4233;
constexpr int Vp = 4352;   // V padded to 34*128 (rows 4233.. are zeros)
constexpr int Ln = 64;     // LMAX
constexpr int Un = 80;     // glg2/pmat row stride (65 used)
constexpr int CS = 68;     // ctc LDS row stride in floats
constexpr int NCB = 34;    // number of 128-wide vocab column blocks
constexpr int Mtot = Bn * Tn;  // 8192

#define LN2     0.6931471805599453f
#define INV_LN2 1.4426950408889634f

typedef __attribute__((ext_vector_type(8))) short short8;
typedef __attribute__((ext_vector_type(4))) float f32x4;

__device__ __forceinline__ float lg2(float x) { return __builtin_amdgcn_logf(x); }
__device__ __forceinline__ float ex2(float x) { return __builtin_amdgcn_exp2f(x); }

__device__ __forceinline__ unsigned short cvt_bf16(float f) {
    unsigned int u = __float_as_uint(f);
    u = (u + 0x7fffu + ((u >> 16) & 1u)) >> 16;
    return (unsigned short)u;
}

// async global->LDS, 16B per lane
__device__ __forceinline__ void gl_lds16(const void* g, void* l) {
    __builtin_amdgcn_global_load_lds(
        (const __attribute__((address_space(1))) void*)g,
        (__attribute__((address_space(3))) void*)l,
        16, 0, 0);
}

// f64 value from lane-1 (wave_shr:1, HW-proven in r0-r5); lane 0 takes 0.0
__device__ __forceinline__ double dpp_shr1_d(double v) {
    union { double d; int i[2]; } u, r;
    u.d = v;
    r.i[0] = __builtin_amdgcn_update_dpp(0, u.i[0], 0x138, 0xF, 0xF, false);
    r.i[1] = __builtin_amdgcn_update_dpp(0, u.i[1], 0x138, 0xF, 0xF, false);
    return r.d;
}

// f64 value from lane+1 (wave_shl:1, mirror of the proven shr); lane 63 takes 0.0
__device__ __forceinline__ double dpp_shl1_d(double v) {
    union { double d; int i[2]; } u, r;
    u.d = v;
    r.i[0] = __builtin_amdgcn_update_dpp(0, u.i[0], 0x130, 0xF, 0xF, false);
    r.i[1] = __builtin_amdgcn_update_dpp(0, u.i[1], 0x130, 0xF, 0xF, false);
    return r.d;
}

// wave-wide int max -> uniform value in all lanes (4 DPP stages + 4 readlanes)
__device__ __forceinline__ int wave_imax(int v) {
    int t;
    t = __builtin_amdgcn_update_dpp(v, v, 0xB1,  0xF, 0xF, false); v = (t > v) ? t : v; // xor1
    t = __builtin_amdgcn_update_dpp(v, v, 0x4E,  0xF, 0xF, false); v = (t > v) ? t : v; // xor2
    t = __builtin_amdgcn_update_dpp(v, v, 0x141, 0xF, 0xF, false); v = (t > v) ? t : v; // xor4
    t = __builtin_amdgcn_update_dpp(v, v, 0x140, 0xF, 0xF, false); v = (t > v) ? t : v; // xor8
    int a = __builtin_amdgcn_readlane(v, 0);
    int b = __builtin_amdgcn_readlane(v, 16);
    int c = __builtin_amdgcn_readlane(v, 32);
    int d = __builtin_amdgcn_readlane(v, 48);
    int ab = (a > b) ? a : b;
    int cd = (c > d) ? c : d;
    return (ab > cd) ? ab : cd;
}

// ---------------- conversion prep (zeroes d_out + pair counters) ----------------
__global__ __launch_bounds__(256) void conv(
    const float* __restrict__ hs, const float* __restrict__ W,
    const float* __restrict__ bias, const int* __restrict__ ys,
    unsigned short* __restrict__ hs_b, unsigned short* __restrict__ w_b,
    float* __restrict__ gbias, float* __restrict__ out, int* __restrict__ pcnt)
{
    const int gid = blockIdx.x * 256 + threadIdx.x;
    const int stride = gridDim.x * 256;
    const float4* hs4 = (const float4*)hs;
    const float4* W4  = (const float4*)W;

    if (gid == 0) out[0] = 0.0f;   // atomic target for ctc_fwd
    if (gid < 16) pcnt[gid] = 0;   // per-batch pair counters (alpha/beta meet)

    for (int i = gid; i < (Bn * Tn * Dn) / 4; i += stride) {
        float4 v = hs4[i];
        ushort4 o = make_ushort4(cvt_bf16(v.x), cvt_bf16(v.y), cvt_bf16(v.z), cvt_bf16(v.w));
        *(ushort4*)(&hs_b[i * 4]) = o;
    }
    for (int i = gid; i < Vp * (Dn / 4); i += stride) {
        int row = i >> 6;
        float4 v = make_float4(0.f, 0.f, 0.f, 0.f);
        if (row < Vn) v = W4[i];
        ushort4 o = make_ushort4(cvt_bf16(v.x), cvt_bf16(v.y), cvt_bf16(v.z), cvt_bf16(v.w));
        *(ushort4*)(&w_b[i * 4]) = o;
    }
    for (int i = gid; i < Bn * 128; i += stride) {
        int b = i >> 7;
        int u = i & 127;
        int v = (u == 0) ? 0 : ((u <= Ln) ? ys[b * Ln + u - 1] : -1);
        gbias[i] = (v >= 0) ? bias[v] : 0.0f;
    }
}

// ---------------- unified GEMM (r5 exact: 32KB LDS, 3 blocks/CU) ----------------
__global__ __launch_bounds__(256) void gemm_se(
    const unsigned short* __restrict__ hs_b, const unsigned short* __restrict__ w_b,
    const int* __restrict__ ys, const float* __restrict__ bias,
    const float* __restrict__ gbias, float* __restrict__ sep,
    float* __restrict__ glg2)
{
    __shared__ __align__(16) short lsA[128 * 64];
    __shared__ __align__(16) short lsB[128 * 64];

    const int tid = threadIdx.x;
    const int lane = tid & 63;
    const int w = tid >> 6;
    const int lr = lane & 15;
    const int kq = lane >> 4;
    const int m0 = blockIdx.x * 128;
    const int mw = w * 32;
    const bool gather = (blockIdx.y == NCB);
    const int b = blockIdx.x >> 2;

    const int srow = lane >> 3;
    const int scg  = (lane & 7) ^ (srow & 7);
    const int scol = scg * 8;

    const unsigned short* bptr[4];
    #pragma unroll
    for (int j = 0; j < 4; ++j) {
        int c = w * 4 + j;
        int row = c * 8 + srow;
        int v;
        if (gather) {
            if (row == 0) v = 0;
            else if (row <= Ln) v = ys[b * Ln + row - 1];
            else v = Vn + 32;                 // zero pad row of w_b
        } else {
            v = blockIdx.y * 128 + row;
        }
        bptr[j] = w_b + (size_t)v * Dn + scol;
    }

    f32x4 acc[2][8];
    #pragma unroll
    for (int mf = 0; mf < 2; ++mf)
        #pragma unroll
        for (int nf = 0; nf < 8; ++nf)
            acc[mf][nf] = (f32x4){0.f, 0.f, 0.f, 0.f};

    for (int ks = 0; ks < 4; ++ks) {
        const int k0 = ks * 64;
        __syncthreads();
        #pragma unroll
        for (int j = 0; j < 4; ++j) {
            int c = w * 4 + j;
            int row = c * 8 + srow;
            gl_lds16(hs_b + (size_t)(m0 + row) * Dn + k0 + scol, (char*)lsA + c * 1024);
            gl_lds16(bptr[j] + k0,                               (char*)lsB + c * 1024);
        }
        __syncthreads();

        #pragma unroll
        for (int sub = 0; sub < 2; ++sub) {
            short8 af[2], bf[8];
            #pragma unroll
            for (int mf = 0; mf < 2; ++mf) {
                int row = mw + mf * 16 + lr;
                int cg = (sub * 4 + kq) ^ (row & 7);
                af[mf] = *(const short8*)(&lsA[row * 64 + cg * 8]);
            }
            #pragma unroll
            for (int nf = 0; nf < 8; ++nf) {
                int row = nf * 16 + lr;
                int cg = (sub * 4 + kq) ^ (row & 7);
                bf[nf] = *(const short8*)(&lsB[row * 64 + cg * 8]);
            }
            #pragma unroll
            for (int mf = 0; mf < 2; ++mf)
                #pragma unroll
                for (int nf = 0; nf < 8; ++nf)
                    acc[mf][nf] = __builtin_amdgcn_mfma_f32_16x16x32_bf16(
                        af[mf], bf[nf], acc[mf][nf], 0, 0, 0);
        }
    }

    if (!gather) {
        const int n0 = blockIdx.y * 128;
        float bcol[8]; bool valid[8];
        #pragma unroll
        for (int nf = 0; nf < 8; ++nf) {
            int col = n0 + nf * 16 + lr;
            valid[nf] = (col < Vn);
            bcol[nf] = valid[nf] ? bias[col] : 0.0f;
        }
        #pragma unroll
        for (int mf = 0; mf < 2; ++mf) {
            #pragma unroll
            for (int r = 0; r < 4; ++r) {
                float s = 0.0f;
                #pragma unroll
                for (int nf = 0; nf < 8; ++nf)
                    if (valid[nf]) s += __expf(acc[mf][nf][r] + bcol[nf]);
                #pragma unroll
                for (int off = 1; off < 16; off <<= 1) s += __shfl_xor(s, off, 64);
                if (lr == 0)
                    sep[(size_t)blockIdx.y * Mtot + m0 + mw + mf * 16 + kq * 4 + r] = s;
            }
        }
    } else {
        #pragma unroll
        for (int mf = 0; mf < 2; ++mf) {
            #pragma unroll
            for (int nf = 0; nf < 5; ++nf) {
                int u = nf * 16 + lr;
                float gv = gbias[b * 128 + u];
                #pragma unroll
                for (int r = 0; r < 4; ++r) {
                    int g = m0 + mw + mf * 16 + kq * 4 + r;
                    glg2[(size_t)g * Un + u] = (acc[mf][nf][r] + gv) * INV_LN2;
                }
            }
        }
    }
}

// ---------------- CTC: bidirectional f64 chains + normalizer ----------------
// Blocks 0..15 : ALPHA for batch b — frames 0..255 (init + 255 steps, f64,
//                wave-uniform renorm/32; exact r5 step algebra).
// Blocks 16..31: BETA for batch b — frames 511..256 backward (256 steps);
//                mirror recursion, inflow from lane l+1 via wave_shl DPP.
// Blocks 32..47: normalizer corr from sep (unchanged).
// Alpha & beta meet at t=255: p = sum_s alpha[s]*beta[s]. Second finisher
// (agent-scope counter, no spin) combines with frexp exponent surgery.
// hl != Tn (never in this workload): alpha runs a simple proven-style full
// forward and outputs directly; beta bails.
__global__ __launch_bounds__(256) void ctc_fwd(
    const float* __restrict__ pmat, const float* __restrict__ sep,
    const int* __restrict__ ys, const int* __restrict__ hlens,
    const int* __restrict__ ylens, float* __restrict__ out,
    double* __restrict__ pairws, int* __restrict__ pcnt)
{
    __shared__ __align__(16) union SMem {
        struct {
            float ls[2][64 * CS + 4];
            double shO[64], shE[64], shZ[64];
            int   shX[64];
        } c;
        struct { float wsum[4]; } r;
        struct { double shD[64]; int flag; } p;
    } sm;

    const int tid = threadIdx.x;
    const int l = tid & 63;
    const int w = tid >> 6;

    double* aO = pairws;              // [16][64]
    double* aE = pairws + 1024;
    double* aZ = pairws + 2048;
    double* bOw = pairws + 3072;
    double* bBw = pairws + 4096;
    double* bZw = pairws + 5120;
    int* aX = (int*)(pairws + 6144);
    int* bX = aX + 16;

    if (blockIdx.x >= 32) {
        // ================= normalizer role =================
        const int b = blockIdx.x - 32;
        const int hl = hlens[b];
        float corrAcc = 0.0f;
        #pragma unroll
        for (int j = 0; j < 2; ++j) {
            int t = tid + j * 256;
            float s = 0.0f;
            #pragma unroll
            for (int c = 0; c < NCB; ++c)
                s += sep[(size_t)c * Mtot + b * Tn + t];
            if (t < hl) corrAcc += lg2(s);
        }
        #pragma unroll
        for (int off = 1; off < 64; off <<= 1) corrAcc += __shfl_xor(corrAcc, off, 64);
        if (l == 0) sm.r.wsum[w] = corrAcc;
        __syncthreads();
        if (tid == 0)
            atomicAdd(out, (sm.r.wsum[0] + sm.r.wsum[1] + sm.r.wsum[2] + sm.r.wsum[3])
                           * (LN2 / (float)Bn));
        return;
    }

    const bool isBeta = (blockIdx.x >= 16);
    const int b = blockIdx.x & 15;
    const int hl = hlens[b];
    const float* pm = pmat + (size_t)b * Tn * Un;
    const int yl  = ys[b * Ln + l];

// -------- shared macro sets (expand on local names at use site) --------
#define RENA do { \
        double mm = fmax(fmax(o, e), z); \
        union { double d; unsigned int ui[2]; } um; um.d = mm; \
        int kk = (int)((um.ui[1] >> 20) & 2047u) - 1023; \
        int km = wave_imax(kk); \
        o = ldexp(o, -km); e = ldexp(e, -km); z = ldexp(z, -km); \
        ex += km; \
    } while (0)

#define STEPR(qv, rv) do { \
        double an = dpp_shr1_d(o); \
        double nO = fma(aF, an, o + e) * (rv); \
        double nE = (e + an) * (qv); \
        double nZ = (z + o) * (qv); \
        o = nO; e = nE; z = nZ; \
    } while (0)

#define LDA(base) do { \
        qa0 = (double)buf[(base) * CS];       ra0 = (double)buf[(base) * CS + 1 + l]; \
        qa1 = (double)buf[((base)+1) * CS];   ra1 = (double)buf[((base)+1) * CS + 1 + l]; \
        qa2 = (double)buf[((base)+2) * CS];   ra2 = (double)buf[((base)+2) * CS + 1 + l]; \
        qa3 = (double)buf[((base)+3) * CS];   ra3 = (double)buf[((base)+3) * CS + 1 + l]; \
    } while (0)
#define LDB(base) do { \
        qb0 = (double)buf[(base) * CS];       rb0 = (double)buf[(base) * CS + 1 + l]; \
        qb1 = (double)buf[((base)+1) * CS];   rb1 = (double)buf[((base)+1) * CS + 1 + l]; \
        qb2 = (double)buf[((base)+2) * CS];   rb2 = (double)buf[((base)+2) * CS + 1 + l]; \
        qb3 = (double)buf[((base)+3) * CS];   rb3 = (double)buf[((base)+3) * CS + 1 + l]; \
    } while (0)
#define LDC(base) do { \
        qc0 = (double)buf[(base) * CS];       rc0 = (double)buf[(base) * CS + 1 + l]; \
        qc1 = (double)buf[((base)+1) * CS];   rc1 = (double)buf[((base)+1) * CS + 1 + l]; \
        qc2 = (double)buf[((base)+2) * CS];   rc2 = (double)buf[((base)+2) * CS + 1 + l]; \
        qc3 = (double)buf[((base)+3) * CS];   rc3 = (double)buf[((base)+3) * CS + 1 + l]; \
    } while (0)

#define W4A do { STEPR(qa0,ra0); STEPR(qa1,ra1); STEPR(qa2,ra2); STEPR(qa3,ra3); } while (0)
#define W4B do { STEPR(qb0,rb0); STEPR(qb1,rb1); STEPR(qb2,rb2); STEPR(qb3,rb3); } while (0)
#define W4C do { STEPR(qc0,rc0); STEPR(qc1,rc1); STEPR(qc2,rc2); STEPR(qc3,rc3); } while (0)

#define RENB do { \
        double mm = fmax(fmax(bo, bb), bz); \
        union { double d; unsigned int ui[2]; } um; um.d = mm; \
        int kk = (int)((um.ui[1] >> 20) & 2047u) - 1023; \
        int km = wave_imax(kk); \
        bo = ldexp(bo, -km); bb = ldexp(bb, -km); bz = ldexp(bz, -km); \
        exB += km; \
    } while (0)

#define BSTEP(qv, rv, nv) do { \
        double an = dpp_shl1_d(bo); \
        double t0  = fma(qv, bb, (rv) * bo); \
        double nBb = fma(nv, an, (qv) * bb); \
        double nBz = fma(rv, bo, (qv) * bz); \
        bo = fma(aFn * (nv), an, t0); \
        bb = nBb; bz = nBz; \
    } while (0)

#define BLA(base) do { \
        qa0=(double)buf[(base)*CS];     ra0=(double)buf[(base)*CS+1+l];     na0=(double)buf[(base)*CS+2+l]; \
        qa1=(double)buf[((base)+1)*CS]; ra1=(double)buf[((base)+1)*CS+1+l]; na1=(double)buf[((base)+1)*CS+2+l]; \
        qa2=(double)buf[((base)+2)*CS]; ra2=(double)buf[((base)+2)*CS+1+l]; na2=(double)buf[((base)+2)*CS+2+l]; \
        qa3=(double)buf[((base)+3)*CS]; ra3=(double)buf[((base)+3)*CS+1+l]; na3=(double)buf[((base)+3)*CS+2+l]; \
    } while (0)
#define BLB(base) do { \
        qb0=(double)buf[(base)*CS];     rb0=(double)buf[(base)*CS+1+l];     nb0=(double)buf[(base)*CS+2+l]; \
        qb1=(double)buf[((base)+1)*CS]; rb1=(double)buf[((base)+1)*CS+1+l]; nb1=(double)buf[((base)+1)*CS+2+l]; \
        qb2=(double)buf[((base)+2)*CS]; rb2=(double)buf[((base)+2)*CS+1+l]; nb2=(double)buf[((base)+2)*CS+2+l]; \
        qb3=(double)buf[((base)+3)*CS]; rb3=(double)buf[((base)+3)*CS+1+l]; nb3=(double)buf[((base)+3)*CS+2+l]; \
    } while (0)
#define BLC(base) do { \
        qc0=(double)buf[(base)*CS];     rc0=(double)buf[(base)*CS+1+l];     nc0=(double)buf[(base)*CS+2+l]; \
        qc1=(double)buf[((base)+1)*CS]; rc1=(double)buf[((base)+1)*CS+1+l]; nc1=(double)buf[((base)+1)*CS+2+l]; \
        qc2=(double)buf[((base)+2)*CS]; rc2=(double)buf[((base)+2)*CS+1+l]; nc2=(double)buf[((base)+2)*CS+2+l]; \
        qc3=(double)buf[((base)+3)*CS]; rc3=(double)buf[((base)+3)*CS+1+l]; nc3=(double)buf[((base)+3)*CS+2+l]; \
    } while (0)

#define BW4A do { BSTEP(qa0,ra0,na0); BSTEP(qa1,ra1,na1); BSTEP(qa2,ra2,na2); BSTEP(qa3,ra3,na3); } while (0)
#define BW4B do { BSTEP(qb0,rb0,nb0); BSTEP(qb1,rb1,nb1); BSTEP(qb2,rb2,nb2); BSTEP(qb3,rb3,nb3); } while (0)
#define BW4C do { BSTEP(qc0,rc0,nc0); BSTEP(qc1,rc1,nc1); BSTEP(qc2,rc2,nc2); BSTEP(qc3,rc3,nc3); } while (0)

// combine (second finisher): products via frexp exponent surgery -> no underflow
#define PAIR_COMBINE(myX) do { \
        if (tid == 0) { \
            int old = __hip_atomic_fetch_add(&pcnt[b], 1, __ATOMIC_ACQ_REL, __HIP_MEMORY_SCOPE_AGENT); \
            sm.p.flag = (old == 1); \
        } \
        __syncthreads(); \
        if (!sm.p.flag) return; \
        __threadfence(); \
        int pemaxv = 0; \
        if (tid < 64) { \
            double o_ = aO[b*64+l], e_ = aE[b*64+l], z_ = aZ[b*64+l]; \
            double po = bOw[b*64+l], pb = bBw[b*64+l], pz = bZw[b*64+l]; \
            int e1,e2,e3,e4,e5,e6; \
            double m1 = frexp(o_, &e1), m2 = frexp(po, &e2); \
            double m3 = frexp(e_, &e3), m4 = frexp(pz, &e4); \
            double m5 = frexp(z_, &e5), m6 = frexp(pb, &e6); \
            double q1 = m1*m2; int x1 = e1+e2; \
            double q2 = m3*m4; int x2 = e3+e4; \
            double q3 = (l==63) ? m5*m6 : 0.0; int x3 = e5+e6; \
            int pe = -(1<<30); \
            if (q1 != 0.0) pe = x1; \
            if (q2 != 0.0 && x2 > pe) pe = x2; \
            if (q3 != 0.0 && x3 > pe) pe = x3; \
            pemaxv = wave_imax(pe); \
            double cc = 0.0; \
            if (q1 != 0.0) cc += ldexp(q1, x1 - pemaxv); \
            if (q2 != 0.0) cc += ldexp(q2, x2 - pemaxv); \
            if (q3 != 0.0) cc += ldexp(q3, x3 - pemaxv); \
            sm.p.shD[l] = cc; \
        } \
        __syncthreads(); \
        if (tid == 0) { \
            double s = 0.0; \
            for (int i2 = 0; i2 < 64; ++i2) s += sm.p.shD[i2]; \
            int ext = aX[b] + bX[b] + pemaxv; \
            float ll = (lg2((float)s) + (float)ext) * LN2; \
            atomicAdd(out, -ll / (float)Bn); \
        } \
    } while (0)

    if (isBeta) {
        // ================= BETA role: frames 511..256 backward =================
        if (hl != Tn) return;
        const int Ly = ylens[b];
        const int yn = (l < 63) ? ys[b * Ln + l + 1] : -1;
        const double aFn = ((l < 63) && (yn != yl)) ? 1.0 : 0.0;

        // stage chunk 0: row tt <-> frame 511 - tt
        #pragma unroll
        for (int j = 0; j < 4; ++j) {
            int i = tid + j * 256;
            int tt = i >> 4, u4 = (i & 15) * 4;
            float4 v = *(const float4*)(pm + (size_t)(511 - tt) * Un + u4);
            v.x = ex2(v.x); v.y = ex2(v.y); v.z = ex2(v.z); v.w = ex2(v.w);
            *(float4*)(&sm.c.ls[0][tt * CS + u4]) = v;
        }
        if (tid < 64) {
            sm.c.ls[0][tid * CS + 64] = ex2(pm[(size_t)(511 - tid) * Un + 64]);
            sm.c.ls[0][tid * CS + 65] = 0.0f;     // r[l+1] slot for lane 63
        }
        __syncthreads();

        // init beta_511: 1 at final states 2L-1 (bo, lane L-1), 2L (bb lane L-1 / bz lane L)
        double bo = (l == Ly - 1) ? 1.0 : 0.0;
        double bb = (l == Ly - 1) ? 1.0 : 0.0;
        double bz = (l == Ly)     ? 1.0 : 0.0;
        int exB = 0;

        float4 r4a = make_float4(0.f,0.f,0.f,0.f), r4b = r4a, r4c = r4a, r4d = r4a;
        float r1 = 0.0f;

        double qa0,qa1,qa2,qa3, ra0,ra1,ra2,ra3, na0,na1,na2,na3;
        double qb0,qb1,qb2,qb3, rb0,rb1,rb2,rb3, nb0,nb1,nb2,nb3;
        double qc0,qc1,qc2,qc3, rc0,rc1,rc2,rc3, nc0,nc1,nc2,nc3;

        for (int k = 0; k < 4; ++k) {
            if (k < 3) {
                const int fb = 511 - (k + 1) * 64;
                { int i = tid;       int tt = i >> 4, u4 = (i & 15) * 4;
                  r4a = *(const float4*)(pm + (size_t)(fb - tt) * Un + u4); }
                { int i = tid + 256; int tt = i >> 4, u4 = (i & 15) * 4;
                  r4b = *(const float4*)(pm + (size_t)(fb - tt) * Un + u4); }
                { int i = tid + 512; int tt = i >> 4, u4 = (i & 15) * 4;
                  r4c = *(const float4*)(pm + (size_t)(fb - tt) * Un + u4); }
                { int i = tid + 768; int tt = i >> 4, u4 = (i & 15) * 4;
                  r4d = *(const float4*)(pm + (size_t)(fb - tt) * Un + u4); }
                if (tid < 64) r1 = pm[(size_t)(fb - tid) * Un + 64];
            }

            const float* buf = sm.c.ls[k & 1];

            RENB;
            BLA(0); BLB(4);
            BLC(8);  BW4A;
            BLA(12); BW4B;
            BLB(16); BW4C;
            BLC(20); BW4A;
            BLA(24); BW4B;
            BLB(28); BW4C;
            BLC(32); BW4A;
            BLA(36); BW4B;
            RENB;
            BLB(40); BW4C;
            BLC(44); BW4A;
            BLA(48); BW4B;
            BLB(52); BW4C;
            BLC(56); BW4A;
            BLA(60); BW4B;
            BW4C;
            BW4A;

            if (k < 3) {
                float* dst = sm.c.ls[(k + 1) & 1];
                { int i = tid;       int tt = i >> 4, u4 = (i & 15) * 4; float4 v = r4a;
                  v.x = ex2(v.x); v.y = ex2(v.y); v.z = ex2(v.z); v.w = ex2(v.w);
                  *(float4*)(&dst[tt * CS + u4]) = v; }
                { int i = tid + 256; int tt = i >> 4, u4 = (i & 15) * 4; float4 v = r4b;
                  v.x = ex2(v.x); v.y = ex2(v.y); v.z = ex2(v.z); v.w = ex2(v.w);
                  *(float4*)(&dst[tt * CS + u4]) = v; }
                { int i = tid + 512; int tt = i >> 4, u4 = (i & 15) * 4; float4 v = r4c;
                  v.x = ex2(v.x); v.y = ex2(v.y); v.z = ex2(v.z); v.w = ex2(v.w);
                  *(float4*)(&dst[tt * CS + u4]) = v; }
                { int i = tid + 768; int tt = i >> 4, u4 = (i & 15) * 4; float4 v = r4d;
                  v.x = ex2(v.x); v.y = ex2(v.y); v.z = ex2(v.z); v.w = ex2(v.w);
                  *(float4*)(&dst[tt * CS + u4]) = v; }
                if (tid < 64) {
                    dst[tid * CS + 64] = ex2(r1);
                    dst[tid * CS + 65] = 0.0f;
                }
            }
            __syncthreads();
        }

        if (tid < 64) { bOw[b*64+l] = bo; bBw[b*64+l] = bb; bZw[b*64+l] = bz; }
        if (tid == 0) bX[b] = exB;
        __threadfence();
        __syncthreads();
        PAIR_COMBINE(bX);
        return;
    }

    // ================= ALPHA role =================
    const int ylm = (l >= 1) ? ys[b * Ln + l - 1] : -1;
    const double aF = ((l >= 1) && (yl != ylm)) ? 1.0 : 0.0;

    if (hl != Tn) {
        // correctness-only fallback: simple full forward (never taken here)
        double o = (l == 0) ? (double)ex2(pm[1]) : 0.0;
        double e = (l == 0) ? (double)ex2(pm[0]) : 0.0;
        double z = 0.0;
        int ex = 0;
        #pragma unroll 1
        for (int t = 1; t < Tn; ++t) {
            RENA;
            double q = (double)ex2(pm[(size_t)t * Un]);
            double r = (double)ex2(pm[(size_t)t * Un + 1 + l]);
            double an = dpp_shr1_d(o);
            double nO = fma(aF, an, o + e) * r;
            double nE = (e + an) * q;
            double nZ = (z + o) * q;
            bool act = (t < hl);
            o = act ? nO : o; e = act ? nE : e; z = act ? nZ : z;
        }
        if (tid < 64) { sm.c.shO[l] = o; sm.c.shE[l] = e; sm.c.shZ[l] = z; sm.c.shX[l] = ex; }
        __syncthreads();
        if (tid == 0) {
            int L = ylens[b];
            double vo = sm.c.shO[L - 1]; int xo = sm.c.shX[L - 1];
            double ve; int xe;
            if (L == 64) { ve = sm.c.shZ[63]; xe = sm.c.shX[63]; }
            else         { ve = sm.c.shE[L];  xe = sm.c.shX[L]; }
            int em = (xo > xe) ? xo : xe;
            double s = ldexp(vo, xo - em) + ldexp(ve, xe - em);
            union { double d; unsigned int ui[2]; } us; us.d = s;
            int ks = (int)((us.ui[1] >> 20) & 2047u) - 1023;
            double mant = ldexp(s, -ks);
            float ll = (lg2((float)mant) + (float)(ks + em)) * LN2;
            atomicAdd(out, -ll / (float)Bn);
        }
        return;
    }

    // fast path: frames 0..255 (init + 255 steps, 4 chunks, last = 63 steps)
    #pragma unroll
    for (int j = 0; j < 4; ++j) {
        int i = tid + j * 256;
        int tt = i >> 4, u4 = (i & 15) * 4;
        float4 v = *(const float4*)(pm + (size_t)(1 + tt) * Un + u4);
        v.x = ex2(v.x); v.y = ex2(v.y); v.z = ex2(v.z); v.w = ex2(v.w);
        *(float4*)(&sm.c.ls[0][tt * CS + u4]) = v;
    }
    if (tid < 64) sm.c.ls[0][tid * CS + 64] = ex2(pm[(size_t)(1 + tid) * Un + 64]);
    __syncthreads();

    double o = (l == 0) ? (double)ex2(pm[1]) : 0.0;
    double e = (l == 0) ? (double)ex2(pm[0]) : 0.0;
    double z = 0.0;
    int ex = 0;

    float4 r4a = make_float4(0.f,0.f,0.f,0.f), r4b = r4a, r4c = r4a, r4d = r4a;
    float r1 = 0.0f;

    double qa0, qa1, qa2, qa3, ra0, ra1, ra2, ra3;
    double qb0, qb1, qb2, qb3, rb0, rb1, rb2, rb3;
    double qc0, qc1, qc2, qc3, rc0, rc1, rc2, rc3;

    for (int c = 0; c < 4; ++c) {
        if (c < 3) {
            const int tb = 1 + (c + 1) * 64;
            { int i = tid;       int tt = i >> 4, u4 = (i & 15) * 4;
              r4a = *(const float4*)(pm + (size_t)(tb + tt) * Un + u4); }
            { int i = tid + 256; int tt = i >> 4, u4 = (i & 15) * 4;
              r4b = *(const float4*)(pm + (size_t)(tb + tt) * Un + u4); }
            { int i = tid + 512; int tt = i >> 4, u4 = (i & 15) * 4;
              r4c = *(const float4*)(pm + (size_t)(tb + tt) * Un + u4); }
            { int i = tid + 768; int tt = i >> 4, u4 = (i & 15) * 4;
              r4d = *(const float4*)(pm + (size_t)(tb + tt) * Un + u4); }
            if (tid < 64)
                r1 = pm[(size_t)(tb + tid) * Un + 64];
        }

        const float* buf = sm.c.ls[c & 1];

        if (c < 3) {
            RENA;
            LDA(0); LDB(4);
            LDC(8);  W4A;
            LDA(12); W4B;
            LDB(16); W4C;
            LDC(20); W4A;
            LDA(24); W4B;
            LDB(28); W4C;
            LDC(32); W4A;
            LDA(36); W4B;
            RENA;
            LDB(40); W4C;
            LDC(44); W4A;
            LDA(48); W4B;
            LDB(52); W4C;
            LDC(56); W4A;
            LDA(60); W4B;
            W4C;
            W4A;
        } else {
            // 63 steps: frames 193..255 (row 63 = frame 256 unused)
            RENA;
            LDA(0); LDB(4);
            LDC(8);  W4A;
            LDA(12); W4B;
            LDB(16); W4C;
            LDC(20); W4A;
            LDA(24); W4B;
            LDB(28); W4C;
            LDC(32); W4A;
            LDA(36); W4B;
            RENA;
            LDB(40); W4C;
            LDC(44); W4A;
            LDA(48); W4B;
            LDB(52); W4C;
            LDC(56); W4A;
            LDA(60); W4B;
            W4C;
            STEPR(qa0, ra0); STEPR(qa1, ra1); STEPR(qa2, ra2);
        }

        if (c < 3) {
            float* dst = sm.c.ls[(c + 1) & 1];
            { int i = tid;       int tt = i >> 4, u4 = (i & 15) * 4; float4 v = r4a;
              v.x = ex2(v.x); v.y = ex2(v.y); v.z = ex2(v.z); v.w = ex2(v.w);
              *(float4*)(&dst[tt * CS + u4]) = v; }
            { int i = tid + 256; int tt = i >> 4, u4 = (i & 15) * 4; float4 v = r4b;
              v.x = ex2(v.x); v.y = ex2(v.y); v.z = ex2(v.z); v.w = ex2(v.w);
              *(float4*)(&dst[tt * CS + u4]) = v; }
            { int i = tid + 512; int tt = i >> 4, u4 = (i & 15) * 4; float4 v = r4c;
              v.x = ex2(v.x); v.y = ex2(v.y); v.z = ex2(v.z); v.w = ex2(v.w);
              *(float4*)(&dst[tt * CS + u4]) = v; }
            { int i = tid + 768; int tt = i >> 4, u4 = (i & 15) * 4; float4 v = r4d;
              v.x = ex2(v.x); v.y = ex2(v.y); v.z = ex2(v.z); v.w = ex2(v.w);
              *(float4*)(&dst[tt * CS + u4]) = v; }
            if (tid < 64) dst[tid * CS + 64] = ex2(r1);
        }
        __syncthreads();
    }

    if (tid < 64) { aO[b*64+l] = o; aE[b*64+l] = e; aZ[b*64+l] = z; }
    if (tid == 0) aX[b] = ex;
    __threadfence();
    __syncthreads();
    PAIR_COMBINE(aX);
#undef RENA
#undef STEPR
#undef LDA
#undef LDB
#undef LDC
#undef W4A
#undef W4B
#undef W4C
#undef RENB
#undef BSTEP
#undef BLA
#undef BLB
#undef BLC
#undef BW4A
#undef BW4B
#undef BW4C
#undef PAIR_COMBINE
}

extern "C" void kernel_launch(void* const* d_in, const int* in_sizes, int n_in,
                              void* d_out, int out_size, void* d_ws, size_t ws_size,
                              hipStream_t stream) {
    const float* hs    = (const float*)d_in[0];
    const int*   hlens = (const int*)d_in[1];
    const int*   ys    = (const int*)d_in[2];
    const int*   ylens = (const int*)d_in[3];
    const float* W     = (const float*)d_in[4];
    const float* bias  = (const float*)d_in[5];
    float* out = (float*)d_out;

    char* ws = (char*)d_ws;
    unsigned short* hs_b = (unsigned short*)(ws);                       // 4,194,304 B
    unsigned short* w_b  = (unsigned short*)(ws + 4194304);             // 2,228,224 B
    float* glg2  = (float*)(ws + 6422528);                              // 2,621,440 B
    float* sep   = (float*)(ws + 9043968);                              // 1,114,112 B
    float* gbias = (float*)(ws + 10158080);                             //     8,192 B
    double* pairws = (double*)(ws + 10166272);                          //    49,280 B
    int*    pcnt   = (int*)(ws + 10215552);                             //        64 B

    conv<<<1024, 256, 0, stream>>>(hs, W, bias, ys, hs_b, w_b, gbias, out, pcnt);
    gemm_se<<<dim3(64, NCB + 1), 256, 0, stream>>>(hs_b, w_b, ys, bias, gbias, sep, glg2);
    ctc_fwd<<<48, 256, 0, stream>>>(glg2, sep, ys, hlens, ylens, out, pairws, pcnt);
}

// Round 12
// 112.381 us; speedup vs baseline: 1.2374x; 1.0125x over previous
//
#include <hip/hip_runtime.h>

constexpr int Bn = 16;
constexpr int Tn = 512;
constexpr int Dn = 256;
constexpr int Vn = 4233;
constexpr int Vp = 4352;   // V padded to 34*128 (rows 4233.. are zeros)
constexpr int Ln = 64;     // LMAX
constexpr int Un = 80;     // glg2/pmat row stride (65 used)
constexpr int CS = 68;     // ctc LDS row stride in floats
constexpr int NCB = 34;    // number of 128-wide vocab column blocks
constexpr int Mtot = Bn * Tn;  // 8192

#define LN2     0.6931471805599453f
#define INV_LN2 1.4426950408889634f

typedef __attribute__((ext_vector_type(8))) short short8;
typedef __attribute__((ext_vector_type(4))) float f32x4;

__device__ __forceinline__ float lg2(float x) { return __builtin_amdgcn_logf(x); }
__device__ __forceinline__ float ex2(float x) { return __builtin_amdgcn_exp2f(x); }

__device__ __forceinline__ unsigned short cvt_bf16(float f) {
    unsigned int u = __float_as_uint(f);
    u = (u + 0x7fffu + ((u >> 16) & 1u)) >> 16;
    return (unsigned short)u;
}

// async global->LDS, 16B per lane
__device__ __forceinline__ void gl_lds16(const void* g, void* l) {
    __builtin_amdgcn_global_load_lds(
        (const __attribute__((address_space(1))) void*)g,
        (__attribute__((address_space(3))) void*)l,
        16, 0, 0);
}

// f64 value from lane-1 (wave_shr:1, HW-proven in r0-r5); lane 0 takes 0.0
__device__ __forceinline__ double dpp_shr1_d(double v) {
    union { double d; int i[2]; } u, r;
    u.d = v;
    r.i[0] = __builtin_amdgcn_update_dpp(0, u.i[0], 0x138, 0xF, 0xF, false);
    r.i[1] = __builtin_amdgcn_update_dpp(0, u.i[1], 0x138, 0xF, 0xF, false);
    return r.d;
}

// f64 value from lane+1 (wave_shl:1, mirror of the proven shr); lane 63 takes 0.0
__device__ __forceinline__ double dpp_shl1_d(double v) {
    union { double d; int i[2]; } u, r;
    u.d = v;
    r.i[0] = __builtin_amdgcn_update_dpp(0, u.i[0], 0x130, 0xF, 0xF, false);
    r.i[1] = __builtin_amdgcn_update_dpp(0, u.i[1], 0x130, 0xF, 0xF, false);
    return r.d;
}

// wave-wide int max -> uniform value in all lanes (4 DPP stages + 4 readlanes)
__device__ __forceinline__ int wave_imax(int v) {
    int t;
    t = __builtin_amdgcn_update_dpp(v, v, 0xB1,  0xF, 0xF, false); v = (t > v) ? t : v; // xor1
    t = __builtin_amdgcn_update_dpp(v, v, 0x4E,  0xF, 0xF, false); v = (t > v) ? t : v; // xor2
    t = __builtin_amdgcn_update_dpp(v, v, 0x141, 0xF, 0xF, false); v = (t > v) ? t : v; // xor4
    t = __builtin_amdgcn_update_dpp(v, v, 0x140, 0xF, 0xF, false); v = (t > v) ? t : v; // xor8
    int a = __builtin_amdgcn_readlane(v, 0);
    int b = __builtin_amdgcn_readlane(v, 16);
    int c = __builtin_amdgcn_readlane(v, 32);
    int d = __builtin_amdgcn_readlane(v, 48);
    int ab = (a > b) ? a : b;
    int cd = (c > d) ? c : d;
    return (ab > cd) ? ab : cd;
}

// ---------------- conversion prep (zeroes d_out + pair counters) ----------------
__global__ __launch_bounds__(256) void conv(
    const float* __restrict__ hs, const float* __restrict__ W,
    const float* __restrict__ bias, const int* __restrict__ ys,
    unsigned short* __restrict__ hs_b, unsigned short* __restrict__ w_b,
    float* __restrict__ gbias, float* __restrict__ out, int* __restrict__ pcnt)
{
    const int gid = blockIdx.x * 256 + threadIdx.x;
    const int stride = gridDim.x * 256;
    const float4* hs4 = (const float4*)hs;
    const float4* W4  = (const float4*)W;

    if (gid == 0) out[0] = 0.0f;   // atomic target for ctc_fwd
    if (gid < 16) pcnt[gid] = 0;   // per-batch pair counters (alpha/beta meet)

    for (int i = gid; i < (Bn * Tn * Dn) / 4; i += stride) {
        float4 v = hs4[i];
        ushort4 o = make_ushort4(cvt_bf16(v.x), cvt_bf16(v.y), cvt_bf16(v.z), cvt_bf16(v.w));
        *(ushort4*)(&hs_b[i * 4]) = o;
    }
    for (int i = gid; i < Vp * (Dn / 4); i += stride) {
        int row = i >> 6;
        float4 v = make_float4(0.f, 0.f, 0.f, 0.f);
        if (row < Vn) v = W4[i];
        ushort4 o = make_ushort4(cvt_bf16(v.x), cvt_bf16(v.y), cvt_bf16(v.z), cvt_bf16(v.w));
        *(ushort4*)(&w_b[i * 4]) = o;
    }
    for (int i = gid; i < Bn * 128; i += stride) {
        int b = i >> 7;
        int u = i & 127;
        int v = (u == 0) ? 0 : ((u <= Ln) ? ys[b * Ln + u - 1] : -1);
        gbias[i] = (v >= 0) ? bias[v] : 0.0f;
    }
}

// ---------------- unified GEMM (r5 structure, forced 4 blocks/CU) ----------------
// Occupancy lever: r5 was VGPR-limited to 3 blocks/CU (132 VGPR, 4 over the
// 128 boundary). __launch_bounds__(256,4) = 4 waves/SIMD -> allocator targets
// <=128 VGPR -> 4 blocks/CU (LDS: 4 x 32KB = 128 <= 160KB). bptr[] pointers
// replaced with 32-bit element offsets to genuinely free 4 VGPRs.
__global__ __launch_bounds__(256, 4) void gemm_se(
    const unsigned short* __restrict__ hs_b, const unsigned short* __restrict__ w_b,
    const int* __restrict__ ys, const float* __restrict__ bias,
    const float* __restrict__ gbias, float* __restrict__ sep,
    float* __restrict__ glg2)
{
    __shared__ __align__(16) short lsA[128 * 64];
    __shared__ __align__(16) short lsB[128 * 64];

    const int tid = threadIdx.x;
    const int lane = tid & 63;
    const int w = tid >> 6;
    const int lr = lane & 15;
    const int kq = lane >> 4;
    const int m0 = blockIdx.x * 128;
    const int mw = w * 32;
    const bool gather = (blockIdx.y == NCB);
    const int b = blockIdx.x >> 2;

    const int srow = lane >> 3;
    const int scg  = (lane & 7) ^ (srow & 7);
    const int scol = scg * 8;

    int boff[4];   // 32-bit element offsets into w_b (max ~1.09M, fits easily)
    #pragma unroll
    for (int j = 0; j < 4; ++j) {
        int c = w * 4 + j;
        int row = c * 8 + srow;
        int v;
        if (gather) {
            if (row == 0) v = 0;
            else if (row <= Ln) v = ys[b * Ln + row - 1];
            else v = Vn + 32;                 // zero pad row of w_b
        } else {
            v = blockIdx.y * 128 + row;
        }
        boff[j] = v * Dn + scol;
    }

    f32x4 acc[2][8];
    #pragma unroll
    for (int mf = 0; mf < 2; ++mf)
        #pragma unroll
        for (int nf = 0; nf < 8; ++nf)
            acc[mf][nf] = (f32x4){0.f, 0.f, 0.f, 0.f};

    for (int ks = 0; ks < 4; ++ks) {
        const int k0 = ks * 64;
        __syncthreads();
        #pragma unroll
        for (int j = 0; j < 4; ++j) {
            int c = w * 4 + j;
            int row = c * 8 + srow;
            gl_lds16(hs_b + (size_t)(m0 + row) * Dn + k0 + scol, (char*)lsA + c * 1024);
            gl_lds16(w_b + boff[j] + k0,                         (char*)lsB + c * 1024);
        }
        __syncthreads();

        #pragma unroll
        for (int sub = 0; sub < 2; ++sub) {
            short8 af[2], bf[8];
            #pragma unroll
            for (int mf = 0; mf < 2; ++mf) {
                int row = mw + mf * 16 + lr;
                int cg = (sub * 4 + kq) ^ (row & 7);
                af[mf] = *(const short8*)(&lsA[row * 64 + cg * 8]);
            }
            #pragma unroll
            for (int nf = 0; nf < 8; ++nf) {
                int row = nf * 16 + lr;
                int cg = (sub * 4 + kq) ^ (row & 7);
                bf[nf] = *(const short8*)(&lsB[row * 64 + cg * 8]);
            }
            #pragma unroll
            for (int mf = 0; mf < 2; ++mf)
                #pragma unroll
                for (int nf = 0; nf < 8; ++nf)
                    acc[mf][nf] = __builtin_amdgcn_mfma_f32_16x16x32_bf16(
                        af[mf], bf[nf], acc[mf][nf], 0, 0, 0);
        }
    }

    if (!gather) {
        const int n0 = blockIdx.y * 128;
        float bcol[8]; bool valid[8];
        #pragma unroll
        for (int nf = 0; nf < 8; ++nf) {
            int col = n0 + nf * 16 + lr;
            valid[nf] = (col < Vn);
            bcol[nf] = valid[nf] ? bias[col] : 0.0f;
        }
        #pragma unroll
        for (int mf = 0; mf < 2; ++mf) {
            #pragma unroll
            for (int r = 0; r < 4; ++r) {
                float s = 0.0f;
                #pragma unroll
                for (int nf = 0; nf < 8; ++nf)
                    if (valid[nf]) s += __expf(acc[mf][nf][r] + bcol[nf]);
                #pragma unroll
                for (int off = 1; off < 16; off <<= 1) s += __shfl_xor(s, off, 64);
                if (lr == 0)
                    sep[(size_t)blockIdx.y * Mtot + m0 + mw + mf * 16 + kq * 4 + r] = s;
            }
        }
    } else {
        #pragma unroll
        for (int mf = 0; mf < 2; ++mf) {
            #pragma unroll
            for (int nf = 0; nf < 5; ++nf) {
                int u = nf * 16 + lr;
                float gv = gbias[b * 128 + u];
                #pragma unroll
                for (int r = 0; r < 4; ++r) {
                    int g = m0 + mw + mf * 16 + kq * 4 + r;
                    glg2[(size_t)g * Un + u] = (acc[mf][nf][r] + gv) * INV_LN2;
                }
            }
        }
    }
}

// ---------------- CTC: bidirectional f64 chains + normalizer (r11 exact) ----------------
// Blocks 0..15 : ALPHA for batch b — frames 0..255.
// Blocks 16..31: BETA for batch b — frames 511..256 backward (mirror recursion).
// Blocks 32..47: normalizer corr from sep.
// Second finisher combines alpha·beta at t=255 with frexp exponent surgery.
__global__ __launch_bounds__(256) void ctc_fwd(
    const float* __restrict__ pmat, const float* __restrict__ sep,
    const int* __restrict__ ys, const int* __restrict__ hlens,
    const int* __restrict__ ylens, float* __restrict__ out,
    double* __restrict__ pairws, int* __restrict__ pcnt)
{
    __shared__ __align__(16) union SMem {
        struct {
            float ls[2][64 * CS + 4];
            double shO[64], shE[64], shZ[64];
            int   shX[64];
        } c;
        struct { float wsum[4]; } r;
        struct { double shD[64]; int flag; } p;
    } sm;

    const int tid = threadIdx.x;
    const int l = tid & 63;
    const int w = tid >> 6;

    double* aO = pairws;              // [16][64]
    double* aE = pairws + 1024;
    double* aZ = pairws + 2048;
    double* bOw = pairws + 3072;
    double* bBw = pairws + 4096;
    double* bZw = pairws + 5120;
    int* aX = (int*)(pairws + 6144);
    int* bX = aX + 16;

    if (blockIdx.x >= 32) {
        // ================= normalizer role =================
        const int b = blockIdx.x - 32;
        const int hl = hlens[b];
        float corrAcc = 0.0f;
        #pragma unroll
        for (int j = 0; j < 2; ++j) {
            int t = tid + j * 256;
            float s = 0.0f;
            #pragma unroll
            for (int c = 0; c < NCB; ++c)
                s += sep[(size_t)c * Mtot + b * Tn + t];
            if (t < hl) corrAcc += lg2(s);
        }
        #pragma unroll
        for (int off = 1; off < 64; off <<= 1) corrAcc += __shfl_xor(corrAcc, off, 64);
        if (l == 0) sm.r.wsum[w] = corrAcc;
        __syncthreads();
        if (tid == 0)
            atomicAdd(out, (sm.r.wsum[0] + sm.r.wsum[1] + sm.r.wsum[2] + sm.r.wsum[3])
                           * (LN2 / (float)Bn));
        return;
    }

    const bool isBeta = (blockIdx.x >= 16);
    const int b = blockIdx.x & 15;
    const int hl = hlens[b];
    const float* pm = pmat + (size_t)b * Tn * Un;
    const int yl  = ys[b * Ln + l];

// -------- shared macro sets (expand on local names at use site) --------
#define RENA do { \
        double mm = fmax(fmax(o, e), z); \
        union { double d; unsigned int ui[2]; } um; um.d = mm; \
        int kk = (int)((um.ui[1] >> 20) & 2047u) - 1023; \
        int km = wave_imax(kk); \
        o = ldexp(o, -km); e = ldexp(e, -km); z = ldexp(z, -km); \
        ex += km; \
    } while (0)

#define STEPR(qv, rv) do { \
        double an = dpp_shr1_d(o); \
        double nO = fma(aF, an, o + e) * (rv); \
        double nE = (e + an) * (qv); \
        double nZ = (z + o) * (qv); \
        o = nO; e = nE; z = nZ; \
    } while (0)

#define LDA(base) do { \
        qa0 = (double)buf[(base) * CS];       ra0 = (double)buf[(base) * CS + 1 + l]; \
        qa1 = (double)buf[((base)+1) * CS];   ra1 = (double)buf[((base)+1) * CS + 1 + l]; \
        qa2 = (double)buf[((base)+2) * CS];   ra2 = (double)buf[((base)+2) * CS + 1 + l]; \
        qa3 = (double)buf[((base)+3) * CS];   ra3 = (double)buf[((base)+3) * CS + 1 + l]; \
    } while (0)
#define LDB(base) do { \
        qb0 = (double)buf[(base) * CS];       rb0 = (double)buf[(base) * CS + 1 + l]; \
        qb1 = (double)buf[((base)+1) * CS];   rb1 = (double)buf[((base)+1) * CS + 1 + l]; \
        qb2 = (double)buf[((base)+2) * CS];   rb2 = (double)buf[((base)+2) * CS + 1 + l]; \
        qb3 = (double)buf[((base)+3) * CS];   rb3 = (double)buf[((base)+3) * CS + 1 + l]; \
    } while (0)
#define LDC(base) do { \
        qc0 = (double)buf[(base) * CS];       rc0 = (double)buf[(base) * CS + 1 + l]; \
        qc1 = (double)buf[((base)+1) * CS];   rc1 = (double)buf[((base)+1) * CS + 1 + l]; \
        qc2 = (double)buf[((base)+2) * CS];   rc2 = (double)buf[((base)+2) * CS + 1 + l]; \
        qc3 = (double)buf[((base)+3) * CS];   rc3 = (double)buf[((base)+3) * CS + 1 + l]; \
    } while (0)

#define W4A do { STEPR(qa0,ra0); STEPR(qa1,ra1); STEPR(qa2,ra2); STEPR(qa3,ra3); } while (0)
#define W4B do { STEPR(qb0,rb0); STEPR(qb1,rb1); STEPR(qb2,rb2); STEPR(qb3,rb3); } while (0)
#define W4C do { STEPR(qc0,rc0); STEPR(qc1,rc1); STEPR(qc2,rc2); STEPR(qc3,rc3); } while (0)

#define RENB do { \
        double mm = fmax(fmax(bo, bb), bz); \
        union { double d; unsigned int ui[2]; } um; um.d = mm; \
        int kk = (int)((um.ui[1] >> 20) & 2047u) - 1023; \
        int km = wave_imax(kk); \
        bo = ldexp(bo, -km); bb = ldexp(bb, -km); bz = ldexp(bz, -km); \
        exB += km; \
    } while (0)

#define BSTEP(qv, rv, nv) do { \
        double an = dpp_shl1_d(bo); \
        double t0  = fma(qv, bb, (rv) * bo); \
        double nBb = fma(nv, an, (qv) * bb); \
        double nBz = fma(rv, bo, (qv) * bz); \
        bo = fma(aFn * (nv), an, t0); \
        bb = nBb; bz = nBz; \
    } while (0)

#define BLA(base) do { \
        qa0=(double)buf[(base)*CS];     ra0=(double)buf[(base)*CS+1+l];     na0=(double)buf[(base)*CS+2+l]; \
        qa1=(double)buf[((base)+1)*CS]; ra1=(double)buf[((base)+1)*CS+1+l]; na1=(double)buf[((base)+1)*CS+2+l]; \
        qa2=(double)buf[((base)+2)*CS]; ra2=(double)buf[((base)+2)*CS+1+l]; na2=(double)buf[((base)+2)*CS+2+l]; \
        qa3=(double)buf[((base)+3)*CS]; ra3=(double)buf[((base)+3)*CS+1+l]; na3=(double)buf[((base)+3)*CS+2+l]; \
    } while (0)
#define BLB(base) do { \
        qb0=(double)buf[(base)*CS];     rb0=(double)buf[(base)*CS+1+l];     nb0=(double)buf[(base)*CS+2+l]; \
        qb1=(double)buf[((base)+1)*CS]; rb1=(double)buf[((base)+1)*CS+1+l]; nb1=(double)buf[((base)+1)*CS+2+l]; \
        qb2=(double)buf[((base)+2)*CS]; rb2=(double)buf[((base)+2)*CS+1+l]; nb2=(double)buf[((base)+2)*CS+2+l]; \
        qb3=(double)buf[((base)+3)*CS]; rb3=(double)buf[((base)+3)*CS+1+l]; nb3=(double)buf[((base)+3)*CS+2+l]; \
    } while (0)
#define BLC(base) do { \
        qc0=(double)buf[(base)*CS];     rc0=(double)buf[(base)*CS+1+l];     nc0=(double)buf[(base)*CS+2+l]; \
        qc1=(double)buf[((base)+1)*CS]; rc1=(double)buf[((base)+1)*CS+1+l]; nc1=(double)buf[((base)+1)*CS+2+l]; \
        qc2=(double)buf[((base)+2)*CS]; rc2=(double)buf[((base)+2)*CS+1+l]; nc2=(double)buf[((base)+2)*CS+2+l]; \
        qc3=(double)buf[((base)+3)*CS]; rc3=(double)buf[((base)+3)*CS+1+l]; nc3=(double)buf[((base)+3)*CS+2+l]; \
    } while (0)

#define BW4A do { BSTEP(qa0,ra0,na0); BSTEP(qa1,ra1,na1); BSTEP(qa2,ra2,na2); BSTEP(qa3,ra3,na3); } while (0)
#define BW4B do { BSTEP(qb0,rb0,nb0); BSTEP(qb1,rb1,nb1); BSTEP(qb2,rb2,nb2); BSTEP(qb3,rb3,nb3); } while (0)
#define BW4C do { BSTEP(qc0,rc0,nc0); BSTEP(qc1,rc1,nc1); BSTEP(qc2,rc2,nc2); BSTEP(qc3,rc3,nc3); } while (0)

// combine (second finisher): products via frexp exponent surgery -> no underflow
#define PAIR_COMBINE(myX) do { \
        if (tid == 0) { \
            int old = __hip_atomic_fetch_add(&pcnt[b], 1, __ATOMIC_ACQ_REL, __HIP_MEMORY_SCOPE_AGENT); \
            sm.p.flag = (old == 1); \
        } \
        __syncthreads(); \
        if (!sm.p.flag) return; \
        __threadfence(); \
        int pemaxv = 0; \
        if (tid < 64) { \
            double o_ = aO[b*64+l], e_ = aE[b*64+l], z_ = aZ[b*64+l]; \
            double po = bOw[b*64+l], pb = bBw[b*64+l], pz = bZw[b*64+l]; \
            int e1,e2,e3,e4,e5,e6; \
            double m1 = frexp(o_, &e1), m2 = frexp(po, &e2); \
            double m3 = frexp(e_, &e3), m4 = frexp(pz, &e4); \
            double m5 = frexp(z_, &e5), m6 = frexp(pb, &e6); \
            double q1 = m1*m2; int x1 = e1+e2; \
            double q2 = m3*m4; int x2 = e3+e4; \
            double q3 = (l==63) ? m5*m6 : 0.0; int x3 = e5+e6; \
            int pe = -(1<<30); \
            if (q1 != 0.0) pe = x1; \
            if (q2 != 0.0 && x2 > pe) pe = x2; \
            if (q3 != 0.0 && x3 > pe) pe = x3; \
            pemaxv = wave_imax(pe); \
            double cc = 0.0; \
            if (q1 != 0.0) cc += ldexp(q1, x1 - pemaxv); \
            if (q2 != 0.0) cc += ldexp(q2, x2 - pemaxv); \
            if (q3 != 0.0) cc += ldexp(q3, x3 - pemaxv); \
            sm.p.shD[l] = cc; \
        } \
        __syncthreads(); \
        if (tid == 0) { \
            double s = 0.0; \
            for (int i2 = 0; i2 < 64; ++i2) s += sm.p.shD[i2]; \
            int ext = aX[b] + bX[b] + pemaxv; \
            float ll = (lg2((float)s) + (float)ext) * LN2; \
            atomicAdd(out, -ll / (float)Bn); \
        } \
    } while (0)

    if (isBeta) {
        // ================= BETA role: frames 511..256 backward =================
        if (hl != Tn) return;
        const int Ly = ylens[b];
        const int yn = (l < 63) ? ys[b * Ln + l + 1] : -1;
        const double aFn = ((l < 63) && (yn != yl)) ? 1.0 : 0.0;

        // stage chunk 0: row tt <-> frame 511 - tt
        #pragma unroll
        for (int j = 0; j < 4; ++j) {
            int i = tid + j * 256;
            int tt = i >> 4, u4 = (i & 15) * 4;
            float4 v = *(const float4*)(pm + (size_t)(511 - tt) * Un + u4);
            v.x = ex2(v.x); v.y = ex2(v.y); v.z = ex2(v.z); v.w = ex2(v.w);
            *(float4*)(&sm.c.ls[0][tt * CS + u4]) = v;
        }
        if (tid < 64) {
            sm.c.ls[0][tid * CS + 64] = ex2(pm[(size_t)(511 - tid) * Un + 64]);
            sm.c.ls[0][tid * CS + 65] = 0.0f;     // r[l+1] slot for lane 63
        }
        __syncthreads();

        // init beta_511: 1 at final states 2L-1 (bo, lane L-1), 2L (bb lane L-1 / bz lane L)
        double bo = (l == Ly - 1) ? 1.0 : 0.0;
        double bb = (l == Ly - 1) ? 1.0 : 0.0;
        double bz = (l == Ly)     ? 1.0 : 0.0;
        int exB = 0;

        float4 r4a = make_float4(0.f,0.f,0.f,0.f), r4b = r4a, r4c = r4a, r4d = r4a;
        float r1 = 0.0f;

        double qa0,qa1,qa2,qa3, ra0,ra1,ra2,ra3, na0,na1,na2,na3;
        double qb0,qb1,qb2,qb3, rb0,rb1,rb2,rb3, nb0,nb1,nb2,nb3;
        double qc0,qc1,qc2,qc3, rc0,rc1,rc2,rc3, nc0,nc1,nc2,nc3;

        for (int k = 0; k < 4; ++k) {
            if (k < 3) {
                const int fb = 511 - (k + 1) * 64;
                { int i = tid;       int tt = i >> 4, u4 = (i & 15) * 4;
                  r4a = *(const float4*)(pm + (size_t)(fb - tt) * Un + u4); }
                { int i = tid + 256; int tt = i >> 4, u4 = (i & 15) * 4;
                  r4b = *(const float4*)(pm + (size_t)(fb - tt) * Un + u4); }
                { int i = tid + 512; int tt = i >> 4, u4 = (i & 15) * 4;
                  r4c = *(const float4*)(pm + (size_t)(fb - tt) * Un + u4); }
                { int i = tid + 768; int tt = i >> 4, u4 = (i & 15) * 4;
                  r4d = *(const float4*)(pm + (size_t)(fb - tt) * Un + u4); }
                if (tid < 64) r1 = pm[(size_t)(fb - tid) * Un + 64];
            }

            const float* buf = sm.c.ls[k & 1];

            RENB;
            BLA(0); BLB(4);
            BLC(8);  BW4A;
            BLA(12); BW4B;
            BLB(16); BW4C;
            BLC(20); BW4A;
            BLA(24); BW4B;
            BLB(28); BW4C;
            BLC(32); BW4A;
            BLA(36); BW4B;
            RENB;
            BLB(40); BW4C;
            BLC(44); BW4A;
            BLA(48); BW4B;
            BLB(52); BW4C;
            BLC(56); BW4A;
            BLA(60); BW4B;
            BW4C;
            BW4A;

            if (k < 3) {
                float* dst = sm.c.ls[(k + 1) & 1];
                { int i = tid;       int tt = i >> 4, u4 = (i & 15) * 4; float4 v = r4a;
                  v.x = ex2(v.x); v.y = ex2(v.y); v.z = ex2(v.z); v.w = ex2(v.w);
                  *(float4*)(&dst[tt * CS + u4]) = v; }
                { int i = tid + 256; int tt = i >> 4, u4 = (i & 15) * 4; float4 v = r4b;
                  v.x = ex2(v.x); v.y = ex2(v.y); v.z = ex2(v.z); v.w = ex2(v.w);
                  *(float4*)(&dst[tt * CS + u4]) = v; }
                { int i = tid + 512; int tt = i >> 4, u4 = (i & 15) * 4; float4 v = r4c;
                  v.x = ex2(v.x); v.y = ex2(v.y); v.z = ex2(v.z); v.w = ex2(v.w);
                  *(float4*)(&dst[tt * CS + u4]) = v; }
                { int i = tid + 768; int tt = i >> 4, u4 = (i & 15) * 4; float4 v = r4d;
                  v.x = ex2(v.x); v.y = ex2(v.y); v.z = ex2(v.z); v.w = ex2(v.w);
                  *(float4*)(&dst[tt * CS + u4]) = v; }
                if (tid < 64) {
                    dst[tid * CS + 64] = ex2(r1);
                    dst[tid * CS + 65] = 0.0f;
                }
            }
            __syncthreads();
        }

        if (tid < 64) { bOw[b*64+l] = bo; bBw[b*64+l] = bb; bZw[b*64+l] = bz; }
        if (tid == 0) bX[b] = exB;
        __threadfence();
        __syncthreads();
        PAIR_COMBINE(bX);
        return;
    }

    // ================= ALPHA role =================
    const int ylm = (l >= 1) ? ys[b * Ln + l - 1] : -1;
    const double aF = ((l >= 1) && (yl != ylm)) ? 1.0 : 0.0;

    if (hl != Tn) {
        // correctness-only fallback: simple full forward (never taken here)
        double o = (l == 0) ? (double)ex2(pm[1]) : 0.0;
        double e = (l == 0) ? (double)ex2(pm[0]) : 0.0;
        double z = 0.0;
        int ex = 0;
        #pragma unroll 1
        for (int t = 1; t < Tn; ++t) {
            RENA;
            double q = (double)ex2(pm[(size_t)t * Un]);
            double r = (double)ex2(pm[(size_t)t * Un + 1 + l]);
            double an = dpp_shr1_d(o);
            double nO = fma(aF, an, o + e) * r;
            double nE = (e + an) * q;
            double nZ = (z + o) * q;
            bool act = (t < hl);
            o = act ? nO : o; e = act ? nE : e; z = act ? nZ : z;
        }
        if (tid < 64) { sm.c.shO[l] = o; sm.c.shE[l] = e; sm.c.shZ[l] = z; sm.c.shX[l] = ex; }
        __syncthreads();
        if (tid == 0) {
            int L = ylens[b];
            double vo = sm.c.shO[L - 1]; int xo = sm.c.shX[L - 1];
            double ve; int xe;
            if (L == 64) { ve = sm.c.shZ[63]; xe = sm.c.shX[63]; }
            else         { ve = sm.c.shE[L];  xe = sm.c.shX[L]; }
            int em = (xo > xe) ? xo : xe;
            double s = ldexp(vo, xo - em) + ldexp(ve, xe - em);
            union { double d; unsigned int ui[2]; } us; us.d = s;
            int ks = (int)((us.ui[1] >> 20) & 2047u) - 1023;
            double mant = ldexp(s, -ks);
            float ll = (lg2((float)mant) + (float)(ks + em)) * LN2;
            atomicAdd(out, -ll / (float)Bn);
        }
        return;
    }

    // fast path: frames 0..255 (init + 255 steps, 4 chunks, last = 63 steps)
    #pragma unroll
    for (int j = 0; j < 4; ++j) {
        int i = tid + j * 256;
        int tt = i >> 4, u4 = (i & 15) * 4;
        float4 v = *(const float4*)(pm + (size_t)(1 + tt) * Un + u4);
        v.x = ex2(v.x); v.y = ex2(v.y); v.z = ex2(v.z); v.w = ex2(v.w);
        *(float4*)(&sm.c.ls[0][tt * CS + u4]) = v;
    }
    if (tid < 64) sm.c.ls[0][tid * CS + 64] = ex2(pm[(size_t)(1 + tid) * Un + 64]);
    __syncthreads();

    double o = (l == 0) ? (double)ex2(pm[1]) : 0.0;
    double e = (l == 0) ? (double)ex2(pm[0]) : 0.0;
    double z = 0.0;
    int ex = 0;

    float4 r4a = make_float4(0.f,0.f,0.f,0.f), r4b = r4a, r4c = r4a, r4d = r4a;
    float r1 = 0.0f;

    double qa0, qa1, qa2, qa3, ra0, ra1, ra2, ra3;
    double qb0, qb1, qb2, qb3, rb0, rb1, rb2, rb3;
    double qc0, qc1, qc2, qc3, rc0, rc1, rc2, rc3;

    for (int c = 0; c < 4; ++c) {
        if (c < 3) {
            const int tb = 1 + (c + 1) * 64;
            { int i = tid;       int tt = i >> 4, u4 = (i & 15) * 4;
              r4a = *(const float4*)(pm + (size_t)(tb + tt) * Un + u4); }
            { int i = tid + 256; int tt = i >> 4, u4 = (i & 15) * 4;
              r4b = *(const float4*)(pm + (size_t)(tb + tt) * Un + u4); }
            { int i = tid + 512; int tt = i >> 4, u4 = (i & 15) * 4;
              r4c = *(const float4*)(pm + (size_t)(tb + tt) * Un + u4); }
            { int i = tid + 768; int tt = i >> 4, u4 = (i & 15) * 4;
              r4d = *(const float4*)(pm + (size_t)(tb + tt) * Un + u4); }
            if (tid < 64)
                r1 = pm[(size_t)(tb + tid) * Un + 64];
        }

        const float* buf = sm.c.ls[c & 1];

        if (c < 3) {
            RENA;
            LDA(0); LDB(4);
            LDC(8);  W4A;
            LDA(12); W4B;
            LDB(16); W4C;
            LDC(20); W4A;
            LDA(24); W4B;
            LDB(28); W4C;
            LDC(32); W4A;
            LDA(36); W4B;
            RENA;
            LDB(40); W4C;
            LDC(44); W4A;
            LDA(48); W4B;
            LDB(52); W4C;
            LDC(56); W4A;
            LDA(60); W4B;
            W4C;
            W4A;
        } else {
            // 63 steps: frames 193..255 (row 63 = frame 256 unused)
            RENA;
            LDA(0); LDB(4);
            LDC(8);  W4A;
            LDA(12); W4B;
            LDB(16); W4C;
            LDC(20); W4A;
            LDA(24); W4B;
            LDB(28); W4C;
            LDC(32); W4A;
            LDA(36); W4B;
            RENA;
            LDB(40); W4C;
            LDC(44); W4A;
            LDA(48); W4B;
            LDB(52); W4C;
            LDC(56); W4A;
            LDA(60); W4B;
            W4C;
            STEPR(qa0, ra0); STEPR(qa1, ra1); STEPR(qa2, ra2);
        }

        if (c < 3) {
            float* dst = sm.c.ls[(c + 1) & 1];
            { int i = tid;       int tt = i >> 4, u4 = (i & 15) * 4; float4 v = r4a;
              v.x = ex2(v.x); v.y = ex2(v.y); v.z = ex2(v.z); v.w = ex2(v.w);
              *(float4*)(&dst[tt * CS + u4]) = v; }
            { int i = tid + 256; int tt = i >> 4, u4 = (i & 15) * 4; float4 v = r4b;
              v.x = ex2(v.x); v.y = ex2(v.y); v.z = ex2(v.z); v.w = ex2(v.w);
              *(float4*)(&dst[tt * CS + u4]) = v; }
            { int i = tid + 512; int tt = i >> 4, u4 = (i & 15) * 4; float4 v = r4c;
              v.x = ex2(v.x); v.y = ex2(v.y); v.z = ex2(v.z); v.w = ex2(v.w);
              *(float4*)(&dst[tt * CS + u4]) = v; }
            { int i = tid + 768; int tt = i >> 4, u4 = (i & 15) * 4; float4 v = r4d;
              v.x = ex2(v.x); v.y = ex2(v.y); v.z = ex2(v.z); v.w = ex2(v.w);
              *(float4*)(&dst[tt * CS + u4]) = v; }
            if (tid < 64) dst[tid * CS + 64] = ex2(r1);
        }
        __syncthreads();
    }

    if (tid < 64) { aO[b*64+l] = o; aE[b*64+l] = e; aZ[b*64+l] = z; }
    if (tid == 0) aX[b] = ex;
    __threadfence();
    __syncthreads();
    PAIR_COMBINE(aX);
#undef RENA
#undef STEPR
#undef LDA
#undef LDB
#undef LDC
#undef W4A
#undef W4B
#undef W4C
#undef RENB
#undef BSTEP
#undef BLA
#undef BLB
#undef BLC
#undef BW4A
#undef BW4B
#undef BW4C
#undef PAIR_COMBINE
}

extern "C" void kernel_launch(void* const* d_in, const int* in_sizes, int n_in,
                              void* d_out, int out_size, void* d_ws, size_t ws_size,
                              hipStream_t stream) {
    const float* hs    = (const float*)d_in[0];
    const int*   hlens = (const int*)d_in[1];
    const int*   ys    = (const int*)d_in[2];
    const int*   ylens = (const int*)d_in[3];
    const float* W     = (const float*)d_in[4];
    const float* bias  = (const float*)d_in[5];
    float* out = (float*)d_out;

    char* ws = (char*)d_ws;
    unsigned short* hs_b = (unsigned short*)(ws);                       // 4,194,304 B
    unsigned short* w_b  = (unsigned short*)(ws + 4194304);             // 2,228,224 B
    float* glg2  = (float*)(ws + 6422528);                              // 2,621,440 B
    float* sep   = (float*)(ws + 9043968);                              // 1,114,112 B
    float* gbias = (float*)(ws + 10158080);                             //     8,192 B
    double* pairws = (double*)(ws + 10166272);                          //    49,280 B
    int*    pcnt   = (int*)(ws + 10215552);                             //        64 B

    conv<<<1024, 256, 0, stream>>>(hs, W, bias, ys, hs_b, w_b, gbias, out, pcnt);
    gemm_se<<<dim3(64, NCB + 1), 256, 0, stream>>>(hs_b, w_b, ys, bias, gbias, sep, glg2);
    ctc_fwd<<<48, 256, 0, stream>>>(glg2, sep, ys, hlens, ylens, out, pairws, pcnt);
}